// Round 17
// baseline (415.429 us; speedup 1.0000x reference)
//
#include <hip/hip_runtime.h>
#include <hip/hip_bf16.h>
#include <cstddef>
#include <cstdint>

#define NM 50000
#define NA 50000
#define ND 500
#define FEAT 128
#define KDIM 768
#define BATCH 1024
#define NEDGE 1600000
#define MD 128            // ELL row capacity (deg ~ Poisson(32); P(>128) ~ 1e-38)

#define NBIN 196          // ceil(50000/256) node bins of 256 nodes
#define CAP 10240         // records per bin (expected 8163, 23 sigma headroom)
#define F1B 400           // fill_bin blocks (edge part)
#define F1E (NEDGE / F1B) // 4000 edges per block (exact)

#define PB128 391         // ceil(50000/128) blocks per big projection (8 waves x 16 rows)
#define PKT   24          // K tiles (768/32)

typedef __bf16 bf16_t;
typedef bf16_t bf16x8 __attribute__((ext_vector_type(8)));
typedef bf16_t bf16x4 __attribute__((ext_vector_type(4)));
typedef float f32x4 __attribute__((ext_vector_type(4)));
typedef float f32x2 __attribute__((ext_vector_type(2)));
typedef unsigned short u16;
typedef unsigned char u8;

__device__ __forceinline__ float sigf(float x) { return 1.0f / (1.0f + __expf(-x)); }

// ---- fp8 e4m3 (OCP) helpers: HW v_cvt pack/unpack ----
__device__ __forceinline__ float4 dec4fp8(uint32_t w) {
  f32x2 lo = __builtin_amdgcn_cvt_pk_f32_fp8(w, false);
  f32x2 hi = __builtin_amdgcn_cvt_pk_f32_fp8(w, true);
  return make_float4(lo[0], lo[1], hi[0], hi[1]);
}
__device__ __forceinline__ u8 enc1fp8(float a) {
  return (u8)(__builtin_amdgcn_cvt_pk_fp8_f32(a, a, 0, false) & 0xff);
}

// ---------------- fill pass 1 + weight->fragment-major bf16, one dispatch -----
// blocks [0,400): edges -> bin-bucketed packed records; blocks [400,912):
// W[768,128] -> Wf fragment-major: granule g=((c>>4)*24+kt)*64+(kq*16+(c&15)),
// Wf[g*8+j] = W[kt*32+kq*8+j][c]  (so proj's B-load is base+lane*16, coalesced).
__global__ __launch_bounds__(256) void fill_bin_wt(
    const int* __restrict__ src, const int* __restrict__ dst,
    int* __restrict__ bcur, uint32_t* __restrict__ rec,
    const float* __restrict__ W0, const float* __restrict__ W1,
    const float* __restrict__ W2, const float* __restrict__ W3,
    bf16_t* __restrict__ T0, bf16_t* __restrict__ T1,
    bf16_t* __restrict__ T2, bf16_t* __restrict__ T3)
{
  __shared__ uint32_t edg[F1E];      // 16 KB
  __shared__ int hist[2 * NBIN];
  __shared__ int base[2 * NBIN];
  if (blockIdx.x >= F1B) {
    const int b = blockIdx.x - F1B;      // 0..511
    const float* W = (b < 128) ? W0 : (b < 256) ? W1 : (b < 384) ? W2 : W3;
    bf16_t* T      = (b < 128) ? T0 : (b < 256) ? T1 : (b < 384) ? T2 : T3;
    int c = b & 127;
    for (int k = threadIdx.x; k < KDIM; k += 256) {
      int kt = k >> 5, kq = (k >> 3) & 3, j = k & 7;
      size_t g = ((size_t)(c >> 4) * PKT + kt) * 64 + (kq * 16 + (c & 15));
      T[g * 8 + j] = (bf16_t)W[(size_t)k * FEAT + c];
    }
    return;
  }
  const int tid = threadIdx.x;
  for (int i = tid; i < 2 * NBIN; i += 256) hist[i] = 0;
  __syncthreads();
  const int e0 = blockIdx.x * F1E;
  for (int i = tid; i < F1E; i += 256) {
    int s = __builtin_nontemporal_load(&src[e0 + i]);
    int d = __builtin_nontemporal_load(&dst[e0 + i]);
    edg[i] = ((uint32_t)s << 16) | (uint32_t)d;
    atomicAdd(&hist[s >> 8], 1);
    atomicAdd(&hist[NBIN + (d >> 8)], 1);
  }
  __syncthreads();
  for (int i = tid; i < 2 * NBIN; i += 256) {
    int c = hist[i];
    base[i] = c ? atomicAdd(&bcur[i], c) : 0;
    hist[i] = 0;  // reuse as emit cursor
  }
  __syncthreads();
  for (int i = tid; i < F1E; i += 256) {
    uint32_t e = edg[i];
    int s = (int)(e >> 16), d = (int)(e & 0xffffu);
    int bm = s >> 8, ba = NBIN + (d >> 8);
    int rm = base[bm] + atomicAdd(&hist[bm], 1);
    int ra = base[ba] + atomicAdd(&hist[ba], 1);
    if (rm < CAP) rec[(size_t)bm * CAP + rm] = e;
    if (ra < CAP) rec[(size_t)ba * CAP + ra] = ((uint32_t)d << 16) | (uint32_t)s;
  }
}

// ---------------- fill pass 2: records -> ELL rows + degrees + dinv -----------
__global__ __launch_bounds__(256) void fill_ell2(
    const uint32_t* __restrict__ rec, const int* __restrict__ bcur,
    u16* __restrict__ adjm, u16* __restrict__ adja,
    int* __restrict__ cnt_m, int* __restrict__ cnt_a,
    float* __restrict__ dm, float* __restrict__ da)
{
  __shared__ int cnt256[256];
  const int g = blockIdx.x;                 // 0..2*NBIN-1
  const int side = g >= NBIN;
  const int bin = side ? g - NBIN : g;
  u16* adj = side ? adja : adjm;
  int* cnt = side ? cnt_a : cnt_m;
  float* dv = side ? da : dm;
  cnt256[threadIdx.x] = 0;
  __syncthreads();
  int n = bcur[g]; if (n > CAP) n = CAP;
  const uint32_t* rb = rec + (size_t)g * CAP;
  for (int i = threadIdx.x; i < n; i += 256) {
    uint32_t r = rb[i];
    int node = (int)(r >> 16);
    int rk = atomicAdd(&cnt256[node & 255], 1);
    if (rk < MD) adj[(size_t)node * MD + rk] = (u16)(r & 0xffffu);
  }
  __syncthreads();
  int node = bin * 256 + threadIdx.x;
  if (node < NM) {
    int c = cnt256[threadIdx.x];
    cnt[node] = c;
    dv[node] = c > 0 ? rsqrtf((float)c) : 0.f;
  }
}

// ---------------- projection, BM=128, 8 waves, ZERO barriers ------------------
// C = sigmoid(A[M,768] @ W + b). OM: 0 = fp32 out, 2 = fp8 out (row-scaled).
// Wave w owns rows [w*16,w*16+16). A: coalesced float4 loads -> cvt ->
// wave-PRIVATE padded LDS (stride 80B, ~2-way) -> one ds_read_b128 fragment.
// B: register-direct from fragment-major global (L2-resident), base+lane*16.
// No cross-wave data sharing => no s_barrier anywhere; compiler pipelines
// loads across K-iterations freely.
template<int OM>
__device__ __forceinline__ void proj8(
    char* smraw,
    const float* __restrict__ A, const bf16_t* __restrict__ Wf,
    const float* __restrict__ bias, void* __restrict__ Cout, int M, int rowBase,
    const float* __restrict__ rowscale, bf16_t* __restrict__ C2)
{
  const int tid = threadIdx.x;
  const int lane = tid & 63;
  const int wid = tid >> 6;                 // 0..7
  char* lb = smraw + wid * 2560;            // 2 stages x 1280B, wave-private

  int r0g = rowBase + wid * 16 + (lane >> 3);
  int r1g = r0g + 8;
  if (r0g > M - 1) r0g = M - 1;
  if (r1g > M - 1) r1g = M - 1;
  const float* ap0 = A + (size_t)r0g * KDIM + (lane & 7) * 4;
  const float* ap1 = A + (size_t)r1g * KDIM + (lane & 7) * 4;

  f32x4 acc[8];
  #pragma unroll
  for (int n = 0; n < 8; ++n) acc[n] = (f32x4){0.f, 0.f, 0.f, 0.f};

  const int wb0 = (lane >> 3) * 80 + (lane & 7) * 8;        // piece0 (rows 0..7)
  const int wb1 = ((lane >> 3) + 8) * 80 + (lane & 7) * 8;  // piece1 (rows 8..15)
  const int rdOff = (lane & 15) * 80 + (lane >> 4) * 16;    // fragment read

  float4 a0 = *(const float4*)ap0;
  float4 a1 = *(const float4*)ap1;

  for (int kt = 0; kt < PKT; ++kt) {
    float4 n0, n1;
    if (kt + 1 < PKT) {
      n0 = *(const float4*)(ap0 + (kt + 1) * 32);
      n1 = *(const float4*)(ap1 + (kt + 1) * 32);
    }
    char* sb = lb + (kt & 1) * 1280;
    bf16x4 w0, w1;
    w0[0] = (bf16_t)a0.x; w0[1] = (bf16_t)a0.y; w0[2] = (bf16_t)a0.z; w0[3] = (bf16_t)a0.w;
    w1[0] = (bf16_t)a1.x; w1[1] = (bf16_t)a1.y; w1[2] = (bf16_t)a1.z; w1[3] = (bf16_t)a1.w;
    *(bf16x4*)(sb + wb0) = w0;
    *(bf16x4*)(sb + wb1) = w1;
    bf16x8 a = *(const bf16x8*)(sb + rdOff);
    const bf16_t* bp = Wf + ((size_t)kt * 64 + lane) * 8;
    #pragma unroll
    for (int n = 0; n < 8; ++n) {
      bf16x8 bfr = *(const bf16x8*)(bp + (size_t)n * PKT * 64 * 8);
      acc[n] = __builtin_amdgcn_mfma_f32_16x16x32_bf16(a, bfr, acc[n], 0, 0, 0);
    }
    a0 = n0; a1 = n1;
  }

  // C frag layout: col=lane&15, row=(lane>>4)*4+reg
  const int r0 = (lane >> 4) * 4, cc = lane & 15;
  #pragma unroll
  for (int n = 0; n < 8; ++n) {
    int col = n * 16 + cc;
    float bb = bias[col];
    #pragma unroll
    for (int r = 0; r < 4; ++r) {
      int row = rowBase + wid * 16 + r0 + r;
      if (row < M) {
        float v = sigf(acc[n][r] + bb);
        float sc = rowscale ? rowscale[row] : 1.0f;
        if constexpr (OM == 2)
          ((u8*)Cout)[(size_t)row * FEAT + col] = enc1fp8(v * sc);
        else
          ((float*)Cout)[(size_t)row * FEAT + col] = v * sc;
        if (C2) C2[(size_t)row * FEAT + col] = (bf16_t)(0.25f * v);
      }
    }
  }
}

// ---------------- ALL projections, one dispatch (798 blocks x 512 thr) --------
__global__ __launch_bounds__(512, 4) void proj_all(
    const float* __restrict__ mashup, const float* __restrict__ api,
    const float* __restrict__ x, const float* __restrict__ domain,
    const bf16_t* __restrict__ wt0, const bf16_t* __restrict__ wt1,
    const bf16_t* __restrict__ wt2, const bf16_t* __restrict__ wt3,
    const float* __restrict__ bsde, const float* __restrict__ bkey,
    const float* __restrict__ bval, const float* __restrict__ bsie,
    u8* __restrict__ M0y8, u8* __restrict__ y0a8,
    float* __restrict__ vmi, float* __restrict__ vkey, float* __restrict__ vval,
    const float* __restrict__ dm, const float* __restrict__ da,
    bf16_t* __restrict__ outA)
{
  __shared__ alignas(16) char smem[8 * 2560];   // 20KB, wave-private regions
  const int b = blockIdx.x;
  if (b < PB128)
    proj8<2>(smem, mashup, wt0, bsde, M0y8, NM, b * 128, dm, nullptr);
  else if (b < 2 * PB128)
    proj8<2>(smem, api, wt3, bsie, y0a8, NA, (b - PB128) * 128, da, outA);
  else if (b < 2 * PB128 + 8)
    proj8<0>(smem, x, wt0, bsde, vmi, BATCH, (b - 2 * PB128) * 128, nullptr, nullptr);
  else if (b < 2 * PB128 + 12)
    proj8<0>(smem, domain, wt1, bkey, vkey, ND, (b - 2 * PB128 - 8) * 128, nullptr, nullptr);
  else
    proj8<0>(smem, domain, wt2, bval, vval, ND, (b - 2 * PB128 - 12) * 128, nullptr, nullptr);
}

// ---------------- attention (phase-B split across both thread halves) ---------
__global__ __launch_bounds__(256) void attn_kernel(
    const float* __restrict__ vmi, const float* __restrict__ vkey,
    const float* __restrict__ vval, bf16_t* __restrict__ zm)
{
  const int i = blockIdx.x;
  const int tid = threadIdx.x;
  __shared__ float vs[FEAT];
  __shared__ float al[ND];
  __shared__ float red[4];
  __shared__ float ps[256];
  __shared__ float totS;
  if (tid < FEAT) vs[tid] = vmi[(size_t)i * FEAT + tid];
  __syncthreads();
  float part = 0.f;
  for (int j = tid; j < ND; j += 256) {
    const float* kr = vkey + (size_t)j * FEAT;
    float dot = 0.f;
    #pragma unroll 8
    for (int k = 0; k < FEAT; k += 4) {
      float4 kv = *(const float4*)(kr + k);
      dot += vs[k] * kv.x + vs[k + 1] * kv.y + vs[k + 2] * kv.z + vs[k + 3] * kv.w;
    }
    al[j] = dot;
    part += dot;
  }
  #pragma unroll
  for (int o = 32; o > 0; o >>= 1) part += __shfl_down(part, o, 64);
  if ((tid & 63) == 0) red[tid >> 6] = part;
  __syncthreads();
  if (tid == 0) totS = red[0] + red[1] + red[2] + red[3];
  // phase B: thread = (half h, feature f); each half sums 250 of the 500 rows
  const int f = tid & 127, h = tid >> 7;
  float s = 0.f;
  const float* vv = vval + (size_t)h * 250 * FEAT + f;
  #pragma unroll 5
  for (int j = 0; j < 250; ++j) s += al[h * 250 + j] * vv[(size_t)j * FEAT];
  ps[tid] = s;
  __syncthreads();
  if (tid < FEAT) {
    float z = 0.5f * ((ps[tid] + ps[128 + tid]) / totS + vs[tid]);
    zm[(size_t)i * FEAT + tid] = (bf16_t)z;
  }
}

// ---------------- fp8 row-gather: half-wave per alternate neighbor ------------
__device__ __forceinline__ float4 gatherF8(const uint32_t* __restrict__ base32,
                                           const u16* __restrict__ row,
                                           int n, int half)
{
  float4 acc = make_float4(0.f, 0.f, 0.f, 0.f);
  int j = half;
  while (j + 14 < n) {
    int u[8];
    #pragma unroll
    for (int q = 0; q < 8; ++q) u[q] = row[j + 2 * q];
    uint32_t w[8];
    #pragma unroll
    for (int q = 0; q < 8; ++q) w[q] = base32[(size_t)u[q] * 32];
    #pragma unroll
    for (int q = 0; q < 8; ++q) {
      float4 v = dec4fp8(w[q]);
      acc.x += v.x; acc.y += v.y; acc.z += v.z; acc.w += v.w;
    }
    j += 16;
  }
  while (j < n) {
    float4 v = dec4fp8(base32[(size_t)row[j] * 32]);
    acc.x += v.x; acc.y += v.y; acc.z += v.z; acc.w += v.w;
    j += 2;
  }
  return acc;
}

#define REDUCE_HALVES(acc)                    \
  acc.x += __shfl_xor(acc.x, 32);             \
  acc.y += __shfl_xor(acc.y, 32);             \
  acc.z += __shfl_xor(acc.z, 32);             \
  acc.w += __shfl_xor(acc.w, 32);

// ---- pass1 (api side): y01a = y0a + da^2 * sum_{m in N(a)} M0y[m] ------------
__global__ __launch_bounds__(256) void prop_p1(
    const uint32_t* __restrict__ M0y8, const uint32_t* __restrict__ y0a8,
    uint32_t* __restrict__ y01a8,
    const u16* __restrict__ adja, const int* __restrict__ cnt_a,
    const float* __restrict__ da)
{
  const int a = blockIdx.x * 4 + (threadIdx.x >> 6);
  const int lane = threadIdx.x & 63;
  const int half = lane >> 5, sl = lane & 31;
  int n = cnt_a[a]; if (n > MD) n = MD;
  float4 acc = gatherF8(M0y8 + sl, adja + (size_t)a * MD, n, half);
  REDUCE_HALVES(acc)
  if (half == 0) {
    const float d = da[a];
    const float s2 = d * d;
    float4 b = dec4fp8(y0a8[(size_t)a * 32 + sl]);
    uint32_t o = __builtin_amdgcn_cvt_pk_fp8_f32(b.x + s2 * acc.x, b.y + s2 * acc.y, 0, false);
    o = __builtin_amdgcn_cvt_pk_fp8_f32(b.z + s2 * acc.z, b.w + s2 * acc.w, o, true);
    y01a8[(size_t)a * 32 + sl] = o;
  }
}

// ---- pass2 (mashup side): Sy = M0y + dm^2 * sum_{a in N(m)} y01a[a] ----------
__global__ __launch_bounds__(256) void prop_p2(
    const uint32_t* __restrict__ y01a8, const uint32_t* __restrict__ M0y8,
    uint32_t* __restrict__ Sy8,
    const u16* __restrict__ adjm, const int* __restrict__ cnt_m,
    const float* __restrict__ dm)
{
  const int m = blockIdx.x * 4 + (threadIdx.x >> 6);
  const int lane = threadIdx.x & 63;
  const int half = lane >> 5, sl = lane & 31;
  int n = cnt_m[m]; if (n > MD) n = MD;
  float4 acc = gatherF8(y01a8 + sl, adjm + (size_t)m * MD, n, half);
  REDUCE_HALVES(acc)
  if (half == 0) {
    const float d = dm[m];
    const float s2 = d * d;
    float4 b = dec4fp8(M0y8[(size_t)m * 32 + sl]);
    uint32_t o = __builtin_amdgcn_cvt_pk_fp8_f32(b.x + s2 * acc.x, b.y + s2 * acc.y, 0, false);
    o = __builtin_amdgcn_cvt_pk_fp8_f32(b.z + s2 * acc.z, b.w + s2 * acc.w, o, true);
    Sy8[(size_t)m * 32 + sl] = o;
  }
}

// ---- pass3 (api side): O = 0.25*A0 + 0.25*da * sum_{m in N(a)} Sy[m] ---------
__global__ __launch_bounds__(256) void prop_p3(
    const uint32_t* __restrict__ Sy8, const bf16_t* __restrict__ outA,
    bf16_t* __restrict__ Obf,
    const u16* __restrict__ adja, const int* __restrict__ cnt_a,
    const float* __restrict__ da)
{
  const int a = blockIdx.x * 4 + (threadIdx.x >> 6);
  const int lane = threadIdx.x & 63;
  const int half = lane >> 5, sl = lane & 31;
  int n = cnt_a[a]; if (n > MD) n = MD;
  float4 acc = gatherF8(Sy8 + sl, adja + (size_t)a * MD, n, half);
  REDUCE_HALVES(acc)
  if (half == 0) {
    const float q = 0.25f * da[a];
    bf16x4 pv = *(const bf16x4*)(outA + (size_t)a * FEAT + 4 * sl);
    bf16x4 o;
    o[0] = (bf16_t)((float)pv[0] + q * acc.x);
    o[1] = (bf16_t)((float)pv[1] + q * acc.y);
    o[2] = (bf16_t)((float)pv[2] + q * acc.z);
    o[3] = (bf16_t)((float)pv[3] + q * acc.w);
    *(bf16x4*)(Obf + (size_t)a * FEAT + 4 * sl) = o;
  }
}

// ---------------- pred = Z[1024,128] @ O[50000,128]^T, bf16 MFMA --------------
__global__ __launch_bounds__(256) void pred_mfma(
    const bf16_t* __restrict__ Z, const bf16_t* __restrict__ O,
    float* __restrict__ out)
{
  const int lane = threadIdx.x & 63;
  const int wid = threadIdx.x >> 6;
  const int nBase = blockIdx.x * 256 + wid * 64;
  const int cc = lane & 15;
  const int kOff = (lane >> 4) * 8;

  bf16x8 b[4][4];
  #pragma unroll
  for (int n = 0; n < 4; ++n) {
    int c = nBase + n * 16 + cc;
    if (c > NA - 1) c = NA - 1;
    #pragma unroll
    for (int kk = 0; kk < 4; ++kk)
      b[n][kk] = *(const bf16x8*)(O + (size_t)c * FEAT + kk * 32 + kOff);
  }

  const int r0 = (lane >> 4) * 4;
  #pragma unroll
  for (int it = 0; it < 4; ++it) {
    const int iBase = blockIdx.y * 256 + it * 64;
    f32x4 acc[4][4];
    #pragma unroll
    for (int m = 0; m < 4; ++m)
      #pragma unroll
      for (int n = 0; n < 4; ++n)
        acc[m][n] = (f32x4){0.f, 0.f, 0.f, 0.f};

    #pragma unroll
    for (int kk = 0; kk < 4; ++kk) {
      bf16x8 a[4];
      #pragma unroll
      for (int m = 0; m < 4; ++m)
        a[m] = *(const bf16x8*)(Z + (size_t)(iBase + cc + m * 16) * FEAT + kk * 32 + kOff);
      #pragma unroll
      for (int m = 0; m < 4; ++m)
        #pragma unroll
        for (int n = 0; n < 4; ++n)
          acc[m][n] = __builtin_amdgcn_mfma_f32_16x16x32_bf16(a[m], b[n][kk], acc[m][n], 0, 0, 0);
    }

    #pragma unroll
    for (int n = 0; n < 4; ++n) {
      int col = nBase + n * 16 + cc;
      if (col < NA) {
        #pragma unroll
        for (int m = 0; m < 4; ++m) {
          #pragma unroll
          for (int r = 0; r < 4; ++r) {
            int row = iBase + m * 16 + r0 + r;
            __builtin_nontemporal_store(acc[m][n][r], &out[(size_t)row * NA + col]);
          }
        }
      }
    }
  }
}

static inline char* alignup(char* p, size_t a) {
  return (char*)(((uintptr_t)p + a - 1) & ~(uintptr_t)(a - 1));
}

extern "C" void kernel_launch(void* const* d_in, const int* in_sizes, int n_in,
                              void* d_out, int out_size, void* d_ws, size_t ws_size,
                              hipStream_t stream) {
  const float* x      = (const float*)d_in[0];
  const float* mashup = (const float*)d_in[1];
  const float* domain = (const float*)d_in[2];
  const float* api    = (const float*)d_in[3];
  const float* Wsde   = (const float*)d_in[4];
  const float* bsde   = (const float*)d_in[5];
  const float* Wval   = (const float*)d_in[6];
  const float* bval   = (const float*)d_in[7];
  const float* Wkey   = (const float*)d_in[8];
  const float* bkey   = (const float*)d_in[9];
  const float* Wsie   = (const float*)d_in[10];
  const float* bsie   = (const float*)d_in[11];
  const int* esrc     = (const int*)d_in[12];
  const int* edst     = (const int*)d_in[13];
  float* out = (float*)d_out;

  // workspace layout (~90 MB)
  char* p = (char*)d_ws;
  u8*     M0y8  = (u8*)p; p += (size_t)NM * FEAT;                 // 6.4MB
  u8*     y0a8  = (u8*)p; p += (size_t)NA * FEAT;                 // 6.4MB
  u8*     y01a8 = (u8*)p; p += (size_t)NA * FEAT;                 // 6.4MB
  u8*     Sy8   = (u8*)p; p += (size_t)NM * FEAT;                 // 6.4MB
  bf16_t* outA  = (bf16_t*)p; p += (size_t)NA * FEAT * 2;         // 12.8MB
  bf16_t* Obf   = (bf16_t*)p; p += (size_t)NA * FEAT * 2;         // 12.8MB
  u16*    adjm  = (u16*)p;    p += (size_t)NM * MD * 2;           // 12.8MB
  u16*    adja  = (u16*)p;    p += (size_t)NA * MD * 2;           // 12.8MB
  float*  vmi   = (float*)p;  p += (size_t)BATCH * FEAT * 4;
  float*  vkey  = (float*)p;  p += (size_t)ND * FEAT * 4;
  float*  vval  = (float*)p;  p += (size_t)ND * FEAT * 4;
  bf16_t* zm    = (bf16_t*)p; p += (size_t)BATCH * FEAT * 2;
  int* cnt_m = (int*)p; p += (size_t)NM * 4;
  int* cnt_a = (int*)p; p += (size_t)NA * 4;
  float* dm  = (float*)p; p += (size_t)NM * 4;
  float* da  = (float*)p; p += (size_t)NA * 4;
  int* bcur  = (int*)p; p += 512 * 4;
  p = alignup(p, 16);
  bf16_t* wt0 = (bf16_t*)p; p += (size_t)FEAT * KDIM * 2;
  bf16_t* wt1 = (bf16_t*)p; p += (size_t)FEAT * KDIM * 2;
  bf16_t* wt2 = (bf16_t*)p; p += (size_t)FEAT * KDIM * 2;
  bf16_t* wt3 = (bf16_t*)p; p += (size_t)FEAT * KDIM * 2;
  // rec (2*NBIN*CAP*4B = 16.1MB) overlays M0y8+y0a8+y01a8 (19.2MB): dead
  // before proj_all/prop write those (fill_ell2 completes first, same stream).
  uint32_t* rec = (uint32_t*)M0y8;

  hipMemsetAsync(bcur, 0, 512 * sizeof(int), stream);

  // ---- graph build (+ fragment-major weight conversion fused) ----
  fill_bin_wt<<<F1B + 512, 256, 0, stream>>>(esrc, edst, bcur, rec,
                                             Wsde, Wkey, Wval, Wsie,
                                             wt0, wt1, wt2, wt3);
  fill_ell2<<<2 * NBIN, 256, 0, stream>>>(rec, bcur, adjm, adja,
                                          cnt_m, cnt_a, dm, da);

  // ---- ALL projections in one dispatch (798 blocks x 512 thr, barrier-free) ----
  proj_all<<<2 * PB128 + 16, 512, 0, stream>>>(
      mashup, api, x, domain, wt0, wt1, wt2, wt3,
      bsde, bkey, bval, bsie, M0y8, y0a8, vmi, vkey, vval, dm, da, outA);

  attn_kernel<<<BATCH, 256, 0, stream>>>(vmi, vkey, vval, zm);

  // ---- bipartite LightGCN (fp8 gathers): out_api = 0.25*(A0 + P^T(M0+M1+M2)) ----
  prop_p1<<<NA / 4, 256, 0, stream>>>((const uint32_t*)M0y8, (const uint32_t*)y0a8,
                                      (uint32_t*)y01a8, adja, cnt_a, da);
  prop_p2<<<NM / 4, 256, 0, stream>>>((const uint32_t*)y01a8, (const uint32_t*)M0y8,
                                      (uint32_t*)Sy8, adjm, cnt_m, dm);
  prop_p3<<<NA / 4, 256, 0, stream>>>((const uint32_t*)Sy8, outA, Obf,
                                      adja, cnt_a, da);

  pred_mfma<<<dim3((NA + 255) / 256, BATCH / 256), 256, 0, stream>>>(zm, Obf, out);
}

// Round 18
// 401.327 us; speedup vs baseline: 1.0351x; 1.0351x over previous
//
#include <hip/hip_runtime.h>
#include <hip/hip_bf16.h>
#include <cstddef>
#include <cstdint>

#define NM 50000
#define NA 50000
#define ND 500
#define FEAT 128
#define KDIM 768
#define BATCH 1024
#define NEDGE 1600000
#define MD 128            // ELL row capacity (deg ~ Poisson(32); P(>128) ~ 1e-38)

#define NBIN 196          // ceil(50000/256) node bins of 256 nodes
#define CAP 10240         // records per bin (expected 8163, 23 sigma headroom)
#define F1B 400           // fill_bin blocks (edge part)
#define F1E (NEDGE / F1B) // 4000 edges per block (exact)

#define PB128 391         // ceil(50000/128) blocks per big projection (8 waves x 16 rows)
#define PKT   24          // K tiles (768/32)

typedef __bf16 bf16_t;
typedef bf16_t bf16x8 __attribute__((ext_vector_type(8)));
typedef bf16_t bf16x4 __attribute__((ext_vector_type(4)));
typedef float f32x4 __attribute__((ext_vector_type(4)));
typedef float f32x2 __attribute__((ext_vector_type(2)));
typedef unsigned short u16;
typedef unsigned char u8;

__device__ __forceinline__ float sigf(float x) { return 1.0f / (1.0f + __expf(-x)); }

// ---- fp8 e4m3 (OCP) helpers: HW v_cvt pack/unpack ----
__device__ __forceinline__ float4 dec4fp8(uint32_t w) {
  f32x2 lo = __builtin_amdgcn_cvt_pk_f32_fp8(w, false);
  f32x2 hi = __builtin_amdgcn_cvt_pk_f32_fp8(w, true);
  return make_float4(lo[0], lo[1], hi[0], hi[1]);
}
__device__ __forceinline__ u8 enc1fp8(float a) {
  return (u8)(__builtin_amdgcn_cvt_pk_fp8_f32(a, a, 0, false) & 0xff);
}

// ---- async global->LDS, 16B per lane (dest = wave-uniform base + lane*16) ----
__device__ __forceinline__ void gll16(const void* g, void* l) {
  __builtin_amdgcn_global_load_lds(
      (const __attribute__((address_space(1))) unsigned int*)g,
      (__attribute__((address_space(3))) unsigned int*)l, 16, 0, 0);
}

// ---------------- fill pass 1 + weight transpose, one dispatch ----------------
__global__ __launch_bounds__(256) void fill_bin_wt(
    const int* __restrict__ src, const int* __restrict__ dst,
    int* __restrict__ bcur, uint32_t* __restrict__ rec,
    const float* __restrict__ W0, const float* __restrict__ W1,
    const float* __restrict__ W2, const float* __restrict__ W3,
    bf16_t* __restrict__ T0, bf16_t* __restrict__ T1,
    bf16_t* __restrict__ T2, bf16_t* __restrict__ T3)
{
  __shared__ uint32_t edg[F1E];      // 16 KB
  __shared__ int hist[2 * NBIN];
  __shared__ int base[2 * NBIN];
  if (blockIdx.x >= F1B) {
    const int b = blockIdx.x - F1B;      // 0..511
    const float* W = (b < 128) ? W0 : (b < 256) ? W1 : (b < 384) ? W2 : W3;
    bf16_t* T      = (b < 128) ? T0 : (b < 256) ? T1 : (b < 384) ? T2 : T3;
    int c = b & 127;
    for (int k = threadIdx.x; k < KDIM; k += 256)
      T[(size_t)c * KDIM + k] = (bf16_t)W[(size_t)k * FEAT + c];
    return;
  }
  const int tid = threadIdx.x;
  for (int i = tid; i < 2 * NBIN; i += 256) hist[i] = 0;
  __syncthreads();
  const int e0 = blockIdx.x * F1E;
  for (int i = tid; i < F1E; i += 256) {
    int s = __builtin_nontemporal_load(&src[e0 + i]);
    int d = __builtin_nontemporal_load(&dst[e0 + i]);
    edg[i] = ((uint32_t)s << 16) | (uint32_t)d;
    atomicAdd(&hist[s >> 8], 1);
    atomicAdd(&hist[NBIN + (d >> 8)], 1);
  }
  __syncthreads();
  for (int i = tid; i < 2 * NBIN; i += 256) {
    int c = hist[i];
    base[i] = c ? atomicAdd(&bcur[i], c) : 0;
    hist[i] = 0;  // reuse as emit cursor
  }
  __syncthreads();
  for (int i = tid; i < F1E; i += 256) {
    uint32_t e = edg[i];
    int s = (int)(e >> 16), d = (int)(e & 0xffffu);
    int bm = s >> 8, ba = NBIN + (d >> 8);
    int rm = base[bm] + atomicAdd(&hist[bm], 1);
    int ra = base[ba] + atomicAdd(&hist[ba], 1);
    if (rm < CAP) rec[(size_t)bm * CAP + rm] = e;
    if (ra < CAP) rec[(size_t)ba * CAP + ra] = ((uint32_t)d << 16) | (uint32_t)s;
  }
}

// ---------------- fill pass 2: records -> ELL rows + degrees + dinv -----------
__global__ __launch_bounds__(256) void fill_ell2(
    const uint32_t* __restrict__ rec, const int* __restrict__ bcur,
    u16* __restrict__ adjm, u16* __restrict__ adja,
    int* __restrict__ cnt_m, int* __restrict__ cnt_a,
    float* __restrict__ dm, float* __restrict__ da)
{
  __shared__ int cnt256[256];
  const int g = blockIdx.x;                 // 0..2*NBIN-1
  const int side = g >= NBIN;
  const int bin = side ? g - NBIN : g;
  u16* adj = side ? adja : adjm;
  int* cnt = side ? cnt_a : cnt_m;
  float* dv = side ? da : dm;
  cnt256[threadIdx.x] = 0;
  __syncthreads();
  int n = bcur[g]; if (n > CAP) n = CAP;
  const uint32_t* rb = rec + (size_t)g * CAP;
  for (int i = threadIdx.x; i < n; i += 256) {
    uint32_t r = rb[i];
    int node = (int)(r >> 16);
    int rk = atomicAdd(&cnt256[node & 255], 1);
    if (rk < MD) adj[(size_t)node * MD + rk] = (u16)(r & 0xffffu);
  }
  __syncthreads();
  int node = bin * 256 + threadIdx.x;
  if (node < NM) {
    int c = cnt256[threadIdx.x];
    cnt[node] = c;
    dv[node] = c > 0 ? rsqrtf((float)c) : 0.f;
  }
}

// ---------------- projection, BM=128, 8 waves, gll + 3-stage ------------------
// C = sigmoid(A[M,768] @ W + b). OM: 0 = fp32 out, 2 = fp8 out (row-scaled).
// Wave w owns rows [w*16,w*16+16) x all 128 cols; stages its own A-frag (2 gll)
// + B-frag w (1 gll) per K-tile. 3 buffers x 24KB; iter kt issues stage kt+2
// then vmcnt(6) (stage kt landed; ~2 iterations of HBM-latency cover).
template<int OM>
__device__ __forceinline__ void proj8(
    char* smraw,
    const float* __restrict__ A, const bf16_t* __restrict__ Wt,
    const float* __restrict__ bias, void* __restrict__ Cout, int M, int rowBase,
    const float* __restrict__ rowscale, bf16_t* __restrict__ C2)
{
  const int tid = threadIdx.x;
  const int lane = tid & 63;
  const int wid = tid >> 6;                 // 0..7

  int arow = rowBase + wid * 16 + (lane & 15); if (arow > M - 1) arow = M - 1;
  const float*  asrc = A  + (size_t)arow * KDIM + ((lane >> 4) * 8);
  const bf16_t* bsrc = Wt + (size_t)(wid * 16 + (lane & 15)) * KDIM + ((lane >> 4) * 8);

  f32x4 acc[8];
  #pragma unroll
  for (int n = 0; n < 8; ++n) acc[n] = (f32x4){0.f, 0.f, 0.f, 0.f};

  // per-stage layout (24KB): [A: 8 frags x 2KB][B: 8 frags x 1KB]
  auto stage = [&](int kt, int s) {
    const int k0 = kt * 32;
    char* base = smraw + s * 24576;
    gll16(asrc + k0,     base + wid * 2048);
    gll16(asrc + k0 + 4, base + wid * 2048 + 1024);
    gll16(bsrc + k0,     base + 16384 + wid * 1024);
  };

  stage(0, 0);
  stage(1, 1);

  for (int kt = 0; kt < PKT; ++kt) {
    if (kt + 2 < PKT) {
      stage(kt + 2, (kt + 2) % 3);
      asm volatile("s_waitcnt vmcnt(6)" ::: "memory");   // stage kt landed
    } else if (kt + 1 < PKT) {
      asm volatile("s_waitcnt vmcnt(3)" ::: "memory");
    } else {
      asm volatile("s_waitcnt vmcnt(0)" ::: "memory");
    }
    __builtin_amdgcn_s_barrier();
    asm volatile("" ::: "memory");

    const char* bb = smraw + (kt % 3) * 24576;
    f32x4 lo = *(const f32x4*)(bb + wid * 2048 + lane * 16);
    f32x4 hi = *(const f32x4*)(bb + wid * 2048 + 1024 + lane * 16);
    bf16x8 a;
    a[0] = (bf16_t)lo[0]; a[1] = (bf16_t)lo[1]; a[2] = (bf16_t)lo[2]; a[3] = (bf16_t)lo[3];
    a[4] = (bf16_t)hi[0]; a[5] = (bf16_t)hi[1]; a[6] = (bf16_t)hi[2]; a[7] = (bf16_t)hi[3];
    #pragma unroll
    for (int n = 0; n < 8; ++n) {
      bf16x8 bfr = *(const bf16x8*)(bb + 16384 + n * 1024 + lane * 16);
      acc[n] = __builtin_amdgcn_mfma_f32_16x16x32_bf16(a, bfr, acc[n], 0, 0, 0);
    }

    asm volatile("" ::: "memory");
    __builtin_amdgcn_s_barrier();
  }

  // C frag layout: col=lane&15, row=(lane>>4)*4+reg
  const int r0 = (lane >> 4) * 4, cc = lane & 15;
  #pragma unroll
  for (int n = 0; n < 8; ++n) {
    int col = n * 16 + cc;
    float bb = bias[col];
    #pragma unroll
    for (int r = 0; r < 4; ++r) {
      int row = rowBase + wid * 16 + r0 + r;
      if (row < M) {
        float v = sigf(acc[n][r] + bb);
        float sc = rowscale ? rowscale[row] : 1.0f;
        if constexpr (OM == 2)
          ((u8*)Cout)[(size_t)row * FEAT + col] = enc1fp8(v * sc);
        else
          ((float*)Cout)[(size_t)row * FEAT + col] = v * sc;
        if (C2) C2[(size_t)row * FEAT + col] = (bf16_t)(0.25f * v);
      }
    }
  }
}

// ---------------- ALL projections, one dispatch (798 blocks x 512 thr) --------
// [0,391): mashup->M0y8(fp8,dm); [391,782): api->y0a8(fp8,da)+outA;
// [782,790): x->vmi; [790,794): domain->vkey; [794,798): domain->vval.
__global__ __launch_bounds__(512, 4) void proj_all(
    const float* __restrict__ mashup, const float* __restrict__ api,
    const float* __restrict__ x, const float* __restrict__ domain,
    const bf16_t* __restrict__ wt0, const bf16_t* __restrict__ wt1,
    const bf16_t* __restrict__ wt2, const bf16_t* __restrict__ wt3,
    const float* __restrict__ bsde, const float* __restrict__ bkey,
    const float* __restrict__ bval, const float* __restrict__ bsie,
    u8* __restrict__ M0y8, u8* __restrict__ y0a8,
    float* __restrict__ vmi, float* __restrict__ vkey, float* __restrict__ vval,
    const float* __restrict__ dm, const float* __restrict__ da,
    bf16_t* __restrict__ outA)
{
  __shared__ alignas(16) char smem[3 * 24576];   // 72KB, shared across branches
  const int b = blockIdx.x;
  if (b < PB128)
    proj8<2>(smem, mashup, wt0, bsde, M0y8, NM, b * 128, dm, nullptr);
  else if (b < 2 * PB128)
    proj8<2>(smem, api, wt3, bsie, y0a8, NA, (b - PB128) * 128, da, outA);
  else if (b < 2 * PB128 + 8)
    proj8<0>(smem, x, wt0, bsde, vmi, BATCH, (b - 2 * PB128) * 128, nullptr, nullptr);
  else if (b < 2 * PB128 + 12)
    proj8<0>(smem, domain, wt1, bkey, vkey, ND, (b - 2 * PB128 - 8) * 128, nullptr, nullptr);
  else
    proj8<0>(smem, domain, wt2, bval, vval, ND, (b - 2 * PB128 - 12) * 128, nullptr, nullptr);
}

// ---------------- attention (phase-B split across both thread halves) ---------
__global__ __launch_bounds__(256) void attn_kernel(
    const float* __restrict__ vmi, const float* __restrict__ vkey,
    const float* __restrict__ vval, bf16_t* __restrict__ zm)
{
  const int i = blockIdx.x;
  const int tid = threadIdx.x;
  __shared__ float vs[FEAT];
  __shared__ float al[ND];
  __shared__ float red[4];
  __shared__ float ps[256];
  __shared__ float totS;
  if (tid < FEAT) vs[tid] = vmi[(size_t)i * FEAT + tid];
  __syncthreads();
  float part = 0.f;
  for (int j = tid; j < ND; j += 256) {
    const float* kr = vkey + (size_t)j * FEAT;
    float dot = 0.f;
    #pragma unroll 8
    for (int k = 0; k < FEAT; k += 4) {
      float4 kv = *(const float4*)(kr + k);
      dot += vs[k] * kv.x + vs[k + 1] * kv.y + vs[k + 2] * kv.z + vs[k + 3] * kv.w;
    }
    al[j] = dot;
    part += dot;
  }
  #pragma unroll
  for (int o = 32; o > 0; o >>= 1) part += __shfl_down(part, o, 64);
  if ((tid & 63) == 0) red[tid >> 6] = part;
  __syncthreads();
  if (tid == 0) totS = red[0] + red[1] + red[2] + red[3];
  // phase B: thread = (half h, feature f); each half sums 250 of the 500 rows
  const int f = tid & 127, h = tid >> 7;
  float s = 0.f;
  const float* vv = vval + (size_t)h * 250 * FEAT + f;
  #pragma unroll 5
  for (int j = 0; j < 250; ++j) s += al[h * 250 + j] * vv[(size_t)j * FEAT];
  ps[tid] = s;
  __syncthreads();
  if (tid < FEAT) {
    float z = 0.5f * ((ps[tid] + ps[128 + tid]) / totS + vs[tid]);
    zm[(size_t)i * FEAT + tid] = (bf16_t)z;
  }
}

// ---------------- fp8 row-gather: half-wave per alternate neighbor ------------
__device__ __forceinline__ float4 gatherF8(const uint32_t* __restrict__ base32,
                                           const u16* __restrict__ row,
                                           int n, int half)
{
  float4 acc = make_float4(0.f, 0.f, 0.f, 0.f);
  int j = half;
  while (j + 14 < n) {
    int u[8];
    #pragma unroll
    for (int q = 0; q < 8; ++q) u[q] = row[j + 2 * q];
    uint32_t w[8];
    #pragma unroll
    for (int q = 0; q < 8; ++q) w[q] = base32[(size_t)u[q] * 32];
    #pragma unroll
    for (int q = 0; q < 8; ++q) {
      float4 v = dec4fp8(w[q]);
      acc.x += v.x; acc.y += v.y; acc.z += v.z; acc.w += v.w;
    }
    j += 16;
  }
  while (j < n) {
    float4 v = dec4fp8(base32[(size_t)row[j] * 32]);
    acc.x += v.x; acc.y += v.y; acc.z += v.z; acc.w += v.w;
    j += 2;
  }
  return acc;
}

#define REDUCE_HALVES(acc)                    \
  acc.x += __shfl_xor(acc.x, 32);             \
  acc.y += __shfl_xor(acc.y, 32);             \
  acc.z += __shfl_xor(acc.z, 32);             \
  acc.w += __shfl_xor(acc.w, 32);

// ---- pass1 (api side): y01a = y0a + da^2 * sum_{m in N(a)} M0y[m] ------------
__global__ __launch_bounds__(256) void prop_p1(
    const uint32_t* __restrict__ M0y8, const uint32_t* __restrict__ y0a8,
    uint32_t* __restrict__ y01a8,
    const u16* __restrict__ adja, const int* __restrict__ cnt_a,
    const float* __restrict__ da)
{
  const int a = blockIdx.x * 4 + (threadIdx.x >> 6);
  const int lane = threadIdx.x & 63;
  const int half = lane >> 5, sl = lane & 31;
  int n = cnt_a[a]; if (n > MD) n = MD;
  float4 acc = gatherF8(M0y8 + sl, adja + (size_t)a * MD, n, half);
  REDUCE_HALVES(acc)
  if (half == 0) {
    const float d = da[a];
    const float s2 = d * d;
    float4 b = dec4fp8(y0a8[(size_t)a * 32 + sl]);
    uint32_t o = __builtin_amdgcn_cvt_pk_fp8_f32(b.x + s2 * acc.x, b.y + s2 * acc.y, 0, false);
    o = __builtin_amdgcn_cvt_pk_fp8_f32(b.z + s2 * acc.z, b.w + s2 * acc.w, o, true);
    y01a8[(size_t)a * 32 + sl] = o;
  }
}

// ---- pass2 (mashup side): Sy = M0y + dm^2 * sum_{a in N(m)} y01a[a] ----------
__global__ __launch_bounds__(256) void prop_p2(
    const uint32_t* __restrict__ y01a8, const uint32_t* __restrict__ M0y8,
    uint32_t* __restrict__ Sy8,
    const u16* __restrict__ adjm, const int* __restrict__ cnt_m,
    const float* __restrict__ dm)
{
  const int m = blockIdx.x * 4 + (threadIdx.x >> 6);
  const int lane = threadIdx.x & 63;
  const int half = lane >> 5, sl = lane & 31;
  int n = cnt_m[m]; if (n > MD) n = MD;
  float4 acc = gatherF8(y01a8 + sl, adjm + (size_t)m * MD, n, half);
  REDUCE_HALVES(acc)
  if (half == 0) {
    const float d = dm[m];
    const float s2 = d * d;
    float4 b = dec4fp8(M0y8[(size_t)m * 32 + sl]);
    uint32_t o = __builtin_amdgcn_cvt_pk_fp8_f32(b.x + s2 * acc.x, b.y + s2 * acc.y, 0, false);
    o = __builtin_amdgcn_cvt_pk_fp8_f32(b.z + s2 * acc.z, b.w + s2 * acc.w, o, true);
    Sy8[(size_t)m * 32 + sl] = o;
  }
}

// ---- pass3 (api side): O = 0.25*A0 + 0.25*da * sum_{m in N(a)} Sy[m] ---------
__global__ __launch_bounds__(256) void prop_p3(
    const uint32_t* __restrict__ Sy8, const bf16_t* __restrict__ outA,
    bf16_t* __restrict__ Obf,
    const u16* __restrict__ adja, const int* __restrict__ cnt_a,
    const float* __restrict__ da)
{
  const int a = blockIdx.x * 4 + (threadIdx.x >> 6);
  const int lane = threadIdx.x & 63;
  const int half = lane >> 5, sl = lane & 31;
  int n = cnt_a[a]; if (n > MD) n = MD;
  float4 acc = gatherF8(Sy8 + sl, adja + (size_t)a * MD, n, half);
  REDUCE_HALVES(acc)
  if (half == 0) {
    const float q = 0.25f * da[a];
    bf16x4 pv = *(const bf16x4*)(outA + (size_t)a * FEAT + 4 * sl);
    bf16x4 o;
    o[0] = (bf16_t)((float)pv[0] + q * acc.x);
    o[1] = (bf16_t)((float)pv[1] + q * acc.y);
    o[2] = (bf16_t)((float)pv[2] + q * acc.z);
    o[3] = (bf16_t)((float)pv[3] + q * acc.w);
    *(bf16x4*)(Obf + (size_t)a * FEAT + 4 * sl) = o;
  }
}

// ---------------- pred = Z[1024,128] @ O[50000,128]^T, bf16 MFMA --------------
__global__ __launch_bounds__(256) void pred_mfma(
    const bf16_t* __restrict__ Z, const bf16_t* __restrict__ O,
    float* __restrict__ out)
{
  const int lane = threadIdx.x & 63;
  const int wid = threadIdx.x >> 6;
  const int nBase = blockIdx.x * 256 + wid * 64;
  const int cc = lane & 15;
  const int kOff = (lane >> 4) * 8;

  bf16x8 b[4][4];
  #pragma unroll
  for (int n = 0; n < 4; ++n) {
    int c = nBase + n * 16 + cc;
    if (c > NA - 1) c = NA - 1;
    #pragma unroll
    for (int kk = 0; kk < 4; ++kk)
      b[n][kk] = *(const bf16x8*)(O + (size_t)c * FEAT + kk * 32 + kOff);
  }

  const int r0 = (lane >> 4) * 4;
  #pragma unroll
  for (int it = 0; it < 4; ++it) {
    const int iBase = blockIdx.y * 256 + it * 64;
    f32x4 acc[4][4];
    #pragma unroll
    for (int m = 0; m < 4; ++m)
      #pragma unroll
      for (int n = 0; n < 4; ++n)
        acc[m][n] = (f32x4){0.f, 0.f, 0.f, 0.f};

    #pragma unroll
    for (int kk = 0; kk < 4; ++kk) {
      bf16x8 a[4];
      #pragma unroll
      for (int m = 0; m < 4; ++m)
        a[m] = *(const bf16x8*)(Z + (size_t)(iBase + cc + m * 16) * FEAT + kk * 32 + kOff);
      #pragma unroll
      for (int m = 0; m < 4; ++m)
        #pragma unroll
        for (int n = 0; n < 4; ++n)
          acc[m][n] = __builtin_amdgcn_mfma_f32_16x16x32_bf16(a[m], b[n][kk], acc[m][n], 0, 0, 0);
    }

    #pragma unroll
    for (int n = 0; n < 4; ++n) {
      int col = nBase + n * 16 + cc;
      if (col < NA) {
        #pragma unroll
        for (int m = 0; m < 4; ++m) {
          #pragma unroll
          for (int r = 0; r < 4; ++r) {
            int row = iBase + m * 16 + r0 + r;
            __builtin_nontemporal_store(acc[m][n][r], &out[(size_t)row * NA + col]);
          }
        }
      }
    }
  }
}

static inline char* alignup(char* p, size_t a) {
  return (char*)(((uintptr_t)p + a - 1) & ~(uintptr_t)(a - 1));
}

extern "C" void kernel_launch(void* const* d_in, const int* in_sizes, int n_in,
                              void* d_out, int out_size, void* d_ws, size_t ws_size,
                              hipStream_t stream) {
  const float* x      = (const float*)d_in[0];
  const float* mashup = (const float*)d_in[1];
  const float* domain = (const float*)d_in[2];
  const float* api    = (const float*)d_in[3];
  const float* Wsde   = (const float*)d_in[4];
  const float* bsde   = (const float*)d_in[5];
  const float* Wval   = (const float*)d_in[6];
  const float* bval   = (const float*)d_in[7];
  const float* Wkey   = (const float*)d_in[8];
  const float* bkey   = (const float*)d_in[9];
  const float* Wsie   = (const float*)d_in[10];
  const float* bsie   = (const float*)d_in[11];
  const int* esrc     = (const int*)d_in[12];
  const int* edst     = (const int*)d_in[13];
  float* out = (float*)d_out;

  // workspace layout (~90 MB)
  char* p = (char*)d_ws;
  u8*     M0y8  = (u8*)p; p += (size_t)NM * FEAT;                 // 6.4MB
  u8*     y0a8  = (u8*)p; p += (size_t)NA * FEAT;                 // 6.4MB
  u8*     y01a8 = (u8*)p; p += (size_t)NA * FEAT;                 // 6.4MB
  u8*     Sy8   = (u8*)p; p += (size_t)NM * FEAT;                 // 6.4MB
  bf16_t* outA  = (bf16_t*)p; p += (size_t)NA * FEAT * 2;         // 12.8MB
  bf16_t* Obf   = (bf16_t*)p; p += (size_t)NA * FEAT * 2;         // 12.8MB
  u16*    adjm  = (u16*)p;    p += (size_t)NM * MD * 2;           // 12.8MB
  u16*    adja  = (u16*)p;    p += (size_t)NA * MD * 2;           // 12.8MB
  float*  vmi   = (float*)p;  p += (size_t)BATCH * FEAT * 4;
  float*  vkey  = (float*)p;  p += (size_t)ND * FEAT * 4;
  float*  vval  = (float*)p;  p += (size_t)ND * FEAT * 4;
  bf16_t* zm    = (bf16_t*)p; p += (size_t)BATCH * FEAT * 2;
  int* cnt_m = (int*)p; p += (size_t)NM * 4;
  int* cnt_a = (int*)p; p += (size_t)NA * 4;
  float* dm  = (float*)p; p += (size_t)NM * 4;
  float* da  = (float*)p; p += (size_t)NA * 4;
  int* bcur  = (int*)p; p += 512 * 4;
  p = alignup(p, 16);
  bf16_t* wt0 = (bf16_t*)p; p += (size_t)FEAT * KDIM * 2;
  bf16_t* wt1 = (bf16_t*)p; p += (size_t)FEAT * KDIM * 2;
  bf16_t* wt2 = (bf16_t*)p; p += (size_t)FEAT * KDIM * 2;
  bf16_t* wt3 = (bf16_t*)p; p += (size_t)FEAT * KDIM * 2;
  // rec (2*NBIN*CAP*4B = 16.1MB) overlays M0y8+y0a8+y01a8 (19.2MB): dead
  // before proj_all/prop write those (fill_ell2 completes first, same stream).
  uint32_t* rec = (uint32_t*)M0y8;

  hipMemsetAsync(bcur, 0, 512 * sizeof(int), stream);

  // ---- graph build (+ weight transpose fused into the same dispatch) ----
  fill_bin_wt<<<F1B + 512, 256, 0, stream>>>(esrc, edst, bcur, rec,
                                             Wsde, Wkey, Wval, Wsie,
                                             wt0, wt1, wt2, wt3);
  fill_ell2<<<2 * NBIN, 256, 0, stream>>>(rec, bcur, adjm, adja,
                                          cnt_m, cnt_a, dm, da);

  // ---- ALL projections in one dispatch (798 blocks x 512 thr, 3-stage) ----
  proj_all<<<2 * PB128 + 16, 512, 0, stream>>>(
      mashup, api, x, domain, wt0, wt1, wt2, wt3,
      bsde, bkey, bval, bsie, M0y8, y0a8, vmi, vkey, vval, dm, da, outA);

  attn_kernel<<<BATCH, 256, 0, stream>>>(vmi, vkey, vval, zm);

  // ---- bipartite LightGCN (fp8 gathers): out_api = 0.25*(A0 + P^T(M0+M1+M2)) ----
  prop_p1<<<NA / 4, 256, 0, stream>>>((const uint32_t*)M0y8, (const uint32_t*)y0a8,
                                      (uint32_t*)y01a8, adja, cnt_a, da);
  prop_p2<<<NM / 4, 256, 0, stream>>>((const uint32_t*)y01a8, (const uint32_t*)M0y8,
                                      (uint32_t*)Sy8, adjm, cnt_m, dm);
  prop_p3<<<NA / 4, 256, 0, stream>>>((const uint32_t*)Sy8, outA, Obf,
                                      adja, cnt_a, da);

  pred_mfma<<<dim3((NA + 255) / 256, BATCH / 256), 256, 0, stream>>>(zm, Obf, out);
}

// Round 19
// 379.111 us; speedup vs baseline: 1.0958x; 1.0586x over previous
//
#include <hip/hip_runtime.h>
#include <hip/hip_bf16.h>
#include <cstddef>
#include <cstdint>

#define NM 50000
#define NA 50000
#define ND 500
#define FEAT 128
#define KDIM 768
#define BATCH 1024
#define NEDGE 1600000
#define MD 128            // ELL row capacity (deg ~ Poisson(32); P(>128) ~ 1e-38)

#define NBIN 196          // ceil(50000/256) node bins of 256 nodes
#define CAP 10240         // records per bin (expected 8163, 23 sigma headroom)
#define F1B 400           // fill_bin blocks (edge part)
#define F1E (NEDGE / F1B) // 4000 edges per block (exact)

#define PB128 391         // ceil(50000/128) blocks per big projection (8 waves x 16 rows)
#define PKT   24          // K tiles (768/32)

typedef __bf16 bf16_t;
typedef bf16_t bf16x8 __attribute__((ext_vector_type(8)));
typedef bf16_t bf16x4 __attribute__((ext_vector_type(4)));
typedef float f32x4 __attribute__((ext_vector_type(4)));
typedef float f32x2 __attribute__((ext_vector_type(2)));
typedef unsigned short u16;
typedef unsigned char u8;

__device__ __forceinline__ float sigf(float x) { return 1.0f / (1.0f + __expf(-x)); }

// ---- fp8 e4m3 (OCP) helpers: HW v_cvt pack/unpack ----
__device__ __forceinline__ float4 dec4fp8(uint32_t w) {
  f32x2 lo = __builtin_amdgcn_cvt_pk_f32_fp8(w, false);
  f32x2 hi = __builtin_amdgcn_cvt_pk_f32_fp8(w, true);
  return make_float4(lo[0], lo[1], hi[0], hi[1]);
}
__device__ __forceinline__ u8 enc1fp8(float a) {
  return (u8)(__builtin_amdgcn_cvt_pk_fp8_f32(a, a, 0, false) & 0xff);
}

// ---- async global->LDS, 16B per lane (dest = wave-uniform base + lane*16) ----
__device__ __forceinline__ void gll16(const void* g, void* l) {
  __builtin_amdgcn_global_load_lds(
      (const __attribute__((address_space(1))) unsigned int*)g,
      (__attribute__((address_space(3))) unsigned int*)l, 16, 0, 0);
}

// ---------------- fill pass 1 + weight transpose, one dispatch ----------------
__global__ __launch_bounds__(256) void fill_bin_wt(
    const int* __restrict__ src, const int* __restrict__ dst,
    int* __restrict__ bcur, uint32_t* __restrict__ rec,
    const float* __restrict__ W0, const float* __restrict__ W1,
    const float* __restrict__ W2, const float* __restrict__ W3,
    bf16_t* __restrict__ T0, bf16_t* __restrict__ T1,
    bf16_t* __restrict__ T2, bf16_t* __restrict__ T3)
{
  __shared__ uint32_t edg[F1E];      // 16 KB
  __shared__ int hist[2 * NBIN];
  __shared__ int base[2 * NBIN];
  if (blockIdx.x >= F1B) {
    const int b = blockIdx.x - F1B;      // 0..511
    const float* W = (b < 128) ? W0 : (b < 256) ? W1 : (b < 384) ? W2 : W3;
    bf16_t* T      = (b < 128) ? T0 : (b < 256) ? T1 : (b < 384) ? T2 : T3;
    int c = b & 127;
    for (int k = threadIdx.x; k < KDIM; k += 256)
      T[(size_t)c * KDIM + k] = (bf16_t)W[(size_t)k * FEAT + c];
    return;
  }
  const int tid = threadIdx.x;
  for (int i = tid; i < 2 * NBIN; i += 256) hist[i] = 0;
  __syncthreads();
  const int e0 = blockIdx.x * F1E;
  for (int i = tid; i < F1E; i += 256) {
    int s = __builtin_nontemporal_load(&src[e0 + i]);
    int d = __builtin_nontemporal_load(&dst[e0 + i]);
    edg[i] = ((uint32_t)s << 16) | (uint32_t)d;
    atomicAdd(&hist[s >> 8], 1);
    atomicAdd(&hist[NBIN + (d >> 8)], 1);
  }
  __syncthreads();
  for (int i = tid; i < 2 * NBIN; i += 256) {
    int c = hist[i];
    base[i] = c ? atomicAdd(&bcur[i], c) : 0;
    hist[i] = 0;  // reuse as emit cursor
  }
  __syncthreads();
  for (int i = tid; i < F1E; i += 256) {
    uint32_t e = edg[i];
    int s = (int)(e >> 16), d = (int)(e & 0xffffu);
    int bm = s >> 8, ba = NBIN + (d >> 8);
    int rm = base[bm] + atomicAdd(&hist[bm], 1);
    int ra = base[ba] + atomicAdd(&hist[ba], 1);
    if (rm < CAP) rec[(size_t)bm * CAP + rm] = e;
    if (ra < CAP) rec[(size_t)ba * CAP + ra] = ((uint32_t)d << 16) | (uint32_t)s;
  }
}

// ---------------- fill pass 2: records -> ELL rows + degrees + dinv -----------
__global__ __launch_bounds__(256) void fill_ell2(
    const uint32_t* __restrict__ rec, const int* __restrict__ bcur,
    u16* __restrict__ adjm, u16* __restrict__ adja,
    int* __restrict__ cnt_m, int* __restrict__ cnt_a,
    float* __restrict__ dm, float* __restrict__ da)
{
  __shared__ int cnt256[256];
  const int g = blockIdx.x;                 // 0..2*NBIN-1
  const int side = g >= NBIN;
  const int bin = side ? g - NBIN : g;
  u16* adj = side ? adja : adjm;
  int* cnt = side ? cnt_a : cnt_m;
  float* dv = side ? da : dm;
  cnt256[threadIdx.x] = 0;
  __syncthreads();
  int n = bcur[g]; if (n > CAP) n = CAP;
  const uint32_t* rb = rec + (size_t)g * CAP;
  for (int i = threadIdx.x; i < n; i += 256) {
    uint32_t r = rb[i];
    int node = (int)(r >> 16);
    int rk = atomicAdd(&cnt256[node & 255], 1);
    if (rk < MD) adj[(size_t)node * MD + rk] = (u16)(r & 0xffffu);
  }
  __syncthreads();
  int node = bin * 256 + threadIdx.x;
  if (node < NM) {
    int c = cnt256[threadIdx.x];
    cnt[node] = c;
    dv[node] = c > 0 ? rsqrtf((float)c) : 0.f;
  }
}

// ---------------- projection, BM=128, 8 waves, FULL-LINE A staging ------------
// C = sigmoid(A[M,768] @ W + b). OM: 0 = fp32 out, 2 = fp8 out (row-scaled).
// Wave w owns rows [w*16,w*16+16). A staged as 8 FULL 128B lines per gll
// (lane l -> row l>>3, chunk (l&7) XOR (row&7)); fragment read applies the
// same XOR => content correct, <=2-way bank aliasing (free). B as in r16
// (L2-resident). 2-stage dbuf, counted vmcnt(3), raw s_barrier.
template<int OM>
__device__ __forceinline__ void proj8(
    char* smraw,
    const float* __restrict__ A, const bf16_t* __restrict__ Wt,
    const float* __restrict__ bias, void* __restrict__ Cout, int M, int rowBase,
    const float* __restrict__ rowscale, bf16_t* __restrict__ C2)
{
  const int tid = threadIdx.x;
  const int lane = tid & 63;
  const int wid = tid >> 6;                 // 0..7

  // A staging: gll#0 rows (lane>>3), gll#1 rows 8+(lane>>3); chunk swizzle
  const int srow = lane >> 3;                         // 0..7
  const int schunk = (lane & 7) ^ srow;               // stored-chunk -> global chunk
  int g0 = rowBase + wid * 16 + srow;     if (g0 > M - 1) g0 = M - 1;
  int g1 = rowBase + wid * 16 + 8 + srow; if (g1 > M - 1) g1 = M - 1;
  const float* asrc0 = A + (size_t)g0 * KDIM + schunk * 4;
  const float* asrc1 = A + (size_t)g1 * KDIM + schunk * 4;
  const bf16_t* bsrc = Wt + (size_t)(wid * 16 + (lane & 15)) * KDIM + ((lane >> 4) * 8);

  f32x4 acc[8];
  #pragma unroll
  for (int n = 0; n < 8; ++n) acc[n] = (f32x4){0.f, 0.f, 0.f, 0.f};

  // per-stage layout (24KB): [A: 8 waves x 2KB][B: 8 waves x 1KB]
  auto stage = [&](int kt, int s) {
    const int k0 = kt * 32;
    char* base = smraw + s * 24576;
    gll16(asrc0 + k0, base + wid * 2048);          // rows 0-7, full lines
    gll16(asrc1 + k0, base + wid * 2048 + 1024);   // rows 8-15, full lines
    gll16(bsrc + k0,  base + 16384 + wid * 1024);
  };

  stage(0, 0);

  // fragment read offsets (XOR-swizzled chunks)
  const int row16 = lane & 15, h = lane >> 4;
  const int rd1 = (row16 & 7) * 128 + ((row16 >> 3) ? 1024 : 0) +
                  ((2 * h) ^ (row16 & 7)) * 16;
  const int rd2 = (row16 & 7) * 128 + ((row16 >> 3) ? 1024 : 0) +
                  ((2 * h + 1) ^ (row16 & 7)) * 16;

  for (int kt = 0; kt < PKT; ++kt) {
    if (kt + 1 < PKT) {
      stage(kt + 1, (kt + 1) & 1);
      asm volatile("s_waitcnt vmcnt(3)" ::: "memory");   // stage kt landed
    } else {
      asm volatile("s_waitcnt vmcnt(0)" ::: "memory");
    }
    __builtin_amdgcn_s_barrier();
    asm volatile("" ::: "memory");

    const char* bb = smraw + (kt & 1) * 24576;
    f32x4 lo = *(const f32x4*)(bb + wid * 2048 + rd1);
    f32x4 hi = *(const f32x4*)(bb + wid * 2048 + rd2);
    bf16x8 a;
    a[0] = (bf16_t)lo[0]; a[1] = (bf16_t)lo[1]; a[2] = (bf16_t)lo[2]; a[3] = (bf16_t)lo[3];
    a[4] = (bf16_t)hi[0]; a[5] = (bf16_t)hi[1]; a[6] = (bf16_t)hi[2]; a[7] = (bf16_t)hi[3];
    #pragma unroll
    for (int n = 0; n < 8; ++n) {
      bf16x8 bfr = *(const bf16x8*)(bb + 16384 + n * 1024 + lane * 16);
      acc[n] = __builtin_amdgcn_mfma_f32_16x16x32_bf16(a, bfr, acc[n], 0, 0, 0);
    }

    asm volatile("" ::: "memory");
    __builtin_amdgcn_s_barrier();
  }

  // C frag layout: col=lane&15, row=(lane>>4)*4+reg
  const int r0 = (lane >> 4) * 4, cc = lane & 15;
  #pragma unroll
  for (int n = 0; n < 8; ++n) {
    int col = n * 16 + cc;
    float bb = bias[col];
    #pragma unroll
    for (int r = 0; r < 4; ++r) {
      int row = rowBase + wid * 16 + r0 + r;
      if (row < M) {
        float v = sigf(acc[n][r] + bb);
        float sc = rowscale ? rowscale[row] : 1.0f;
        if constexpr (OM == 2)
          ((u8*)Cout)[(size_t)row * FEAT + col] = enc1fp8(v * sc);
        else
          ((float*)Cout)[(size_t)row * FEAT + col] = v * sc;
        if (C2) C2[(size_t)row * FEAT + col] = (bf16_t)(0.25f * v);
      }
    }
  }
}

// ---------------- ALL projections, one dispatch (798 blocks x 512 thr) --------
__global__ __launch_bounds__(512, 4) void proj_all(
    const float* __restrict__ mashup, const float* __restrict__ api,
    const float* __restrict__ x, const float* __restrict__ domain,
    const bf16_t* __restrict__ wt0, const bf16_t* __restrict__ wt1,
    const bf16_t* __restrict__ wt2, const bf16_t* __restrict__ wt3,
    const float* __restrict__ bsde, const float* __restrict__ bkey,
    const float* __restrict__ bval, const float* __restrict__ bsie,
    u8* __restrict__ M0y8, u8* __restrict__ y0a8,
    float* __restrict__ vmi, float* __restrict__ vkey, float* __restrict__ vval,
    const float* __restrict__ dm, const float* __restrict__ da,
    bf16_t* __restrict__ outA)
{
  __shared__ alignas(16) char smem[2 * 24576];   // 48KB
  const int b = blockIdx.x;
  if (b < PB128)
    proj8<2>(smem, mashup, wt0, bsde, M0y8, NM, b * 128, dm, nullptr);
  else if (b < 2 * PB128)
    proj8<2>(smem, api, wt3, bsie, y0a8, NA, (b - PB128) * 128, da, outA);
  else if (b < 2 * PB128 + 8)
    proj8<0>(smem, x, wt0, bsde, vmi, BATCH, (b - 2 * PB128) * 128, nullptr, nullptr);
  else if (b < 2 * PB128 + 12)
    proj8<0>(smem, domain, wt1, bkey, vkey, ND, (b - 2 * PB128 - 8) * 128, nullptr, nullptr);
  else
    proj8<0>(smem, domain, wt2, bval, vval, ND, (b - 2 * PB128 - 12) * 128, nullptr, nullptr);
}

// ---------------- fp8 row-gather: half-wave per alternate neighbor ------------
__device__ __forceinline__ float4 gatherF8(const uint32_t* __restrict__ base32,
                                           const u16* __restrict__ row,
                                           int n, int half)
{
  float4 acc = make_float4(0.f, 0.f, 0.f, 0.f);
  int j = half;
  while (j + 14 < n) {
    int u[8];
    #pragma unroll
    for (int q = 0; q < 8; ++q) u[q] = row[j + 2 * q];
    uint32_t w[8];
    #pragma unroll
    for (int q = 0; q < 8; ++q) w[q] = base32[(size_t)u[q] * 32];
    #pragma unroll
    for (int q = 0; q < 8; ++q) {
      float4 v = dec4fp8(w[q]);
      acc.x += v.x; acc.y += v.y; acc.z += v.z; acc.w += v.w;
    }
    j += 16;
  }
  while (j < n) {
    float4 v = dec4fp8(base32[(size_t)row[j] * 32]);
    acc.x += v.x; acc.y += v.y; acc.z += v.z; acc.w += v.w;
    j += 2;
  }
  return acc;
}

#define REDUCE_HALVES(acc)                    \
  acc.x += __shfl_xor(acc.x, 32);             \
  acc.y += __shfl_xor(acc.y, 32);             \
  acc.z += __shfl_xor(acc.z, 32);             \
  acc.w += __shfl_xor(acc.w, 32);

// ---------------- fused: attention (blocks <1024) + prop pass1 (rest) ---------
// Both depend only on proj_all; fusing saves a launch gap and lets the
// memory-bound gather blocks fill the CU tail behind the VALU-bound attn.
__global__ __launch_bounds__(256) void attn_p1(
    const float* __restrict__ vmi, const float* __restrict__ vkey,
    const float* __restrict__ vval, bf16_t* __restrict__ zm,
    const uint32_t* __restrict__ M0y8, const uint32_t* __restrict__ y0a8,
    uint32_t* __restrict__ y01a8,
    const u16* __restrict__ adja, const int* __restrict__ cnt_a,
    const float* __restrict__ da)
{
  const int tid = threadIdx.x;
  if (blockIdx.x >= BATCH) {
    // ---- prop pass1 ----
    const int a = (blockIdx.x - BATCH) * 4 + (tid >> 6);
    const int lane = tid & 63;
    const int half = lane >> 5, sl = lane & 31;
    int n = cnt_a[a]; if (n > MD) n = MD;
    float4 acc = gatherF8(M0y8 + sl, adja + (size_t)a * MD, n, half);
    REDUCE_HALVES(acc)
    if (half == 0) {
      const float d = da[a];
      const float s2 = d * d;
      float4 b = dec4fp8(y0a8[(size_t)a * 32 + sl]);
      uint32_t o = __builtin_amdgcn_cvt_pk_fp8_f32(b.x + s2 * acc.x, b.y + s2 * acc.y, 0, false);
      o = __builtin_amdgcn_cvt_pk_fp8_f32(b.z + s2 * acc.z, b.w + s2 * acc.w, o, true);
      y01a8[(size_t)a * 32 + sl] = o;
    }
    return;
  }
  // ---- attention ----
  const int i = blockIdx.x;
  __shared__ float vs[FEAT];
  __shared__ float al[ND];
  __shared__ float red[4];
  __shared__ float ps[256];
  __shared__ float totS;
  if (tid < FEAT) vs[tid] = vmi[(size_t)i * FEAT + tid];
  __syncthreads();
  float part = 0.f;
  for (int j = tid; j < ND; j += 256) {
    const float* kr = vkey + (size_t)j * FEAT;
    float dot = 0.f;
    #pragma unroll 8
    for (int k = 0; k < FEAT; k += 4) {
      float4 kv = *(const float4*)(kr + k);
      dot += vs[k] * kv.x + vs[k + 1] * kv.y + vs[k + 2] * kv.z + vs[k + 3] * kv.w;
    }
    al[j] = dot;
    part += dot;
  }
  #pragma unroll
  for (int o = 32; o > 0; o >>= 1) part += __shfl_down(part, o, 64);
  if ((tid & 63) == 0) red[tid >> 6] = part;
  __syncthreads();
  if (tid == 0) totS = red[0] + red[1] + red[2] + red[3];
  const int f = tid & 127, h = tid >> 7;
  float s = 0.f;
  const float* vv = vval + (size_t)h * 250 * FEAT + f;
  #pragma unroll 5
  for (int j = 0; j < 250; ++j) s += al[h * 250 + j] * vv[(size_t)j * FEAT];
  ps[tid] = s;
  __syncthreads();
  if (tid < FEAT) {
    float z = 0.5f * ((ps[tid] + ps[128 + tid]) / totS + vs[tid]);
    zm[(size_t)i * FEAT + tid] = (bf16_t)z;
  }
}

// ---- pass2 (mashup side): Sy = M0y + dm^2 * sum_{a in N(m)} y01a[a] ----------
__global__ __launch_bounds__(256) void prop_p2(
    const uint32_t* __restrict__ y01a8, const uint32_t* __restrict__ M0y8,
    uint32_t* __restrict__ Sy8,
    const u16* __restrict__ adjm, const int* __restrict__ cnt_m,
    const float* __restrict__ dm)
{
  const int m = blockIdx.x * 4 + (threadIdx.x >> 6);
  const int lane = threadIdx.x & 63;
  const int half = lane >> 5, sl = lane & 31;
  int n = cnt_m[m]; if (n > MD) n = MD;
  float4 acc = gatherF8(y01a8 + sl, adjm + (size_t)m * MD, n, half);
  REDUCE_HALVES(acc)
  if (half == 0) {
    const float d = dm[m];
    const float s2 = d * d;
    float4 b = dec4fp8(M0y8[(size_t)m * 32 + sl]);
    uint32_t o = __builtin_amdgcn_cvt_pk_fp8_f32(b.x + s2 * acc.x, b.y + s2 * acc.y, 0, false);
    o = __builtin_amdgcn_cvt_pk_fp8_f32(b.z + s2 * acc.z, b.w + s2 * acc.w, o, true);
    Sy8[(size_t)m * 32 + sl] = o;
  }
}

// ---- pass3 (api side): O = 0.25*A0 + 0.25*da * sum_{m in N(a)} Sy[m] ---------
__global__ __launch_bounds__(256) void prop_p3(
    const uint32_t* __restrict__ Sy8, const bf16_t* __restrict__ outA,
    bf16_t* __restrict__ Obf,
    const u16* __restrict__ adja, const int* __restrict__ cnt_a,
    const float* __restrict__ da)
{
  const int a = blockIdx.x * 4 + (threadIdx.x >> 6);
  const int lane = threadIdx.x & 63;
  const int half = lane >> 5, sl = lane & 31;
  int n = cnt_a[a]; if (n > MD) n = MD;
  float4 acc = gatherF8(Sy8 + sl, adja + (size_t)a * MD, n, half);
  REDUCE_HALVES(acc)
  if (half == 0) {
    const float q = 0.25f * da[a];
    bf16x4 pv = *(const bf16x4*)(outA + (size_t)a * FEAT + 4 * sl);
    bf16x4 o;
    o[0] = (bf16_t)((float)pv[0] + q * acc.x);
    o[1] = (bf16_t)((float)pv[1] + q * acc.y);
    o[2] = (bf16_t)((float)pv[2] + q * acc.z);
    o[3] = (bf16_t)((float)pv[3] + q * acc.w);
    *(bf16x4*)(Obf + (size_t)a * FEAT + 4 * sl) = o;
  }
}

// ---------------- pred = Z[1024,128] @ O[50000,128]^T, bf16 MFMA --------------
__global__ __launch_bounds__(256) void pred_mfma(
    const bf16_t* __restrict__ Z, const bf16_t* __restrict__ O,
    float* __restrict__ out)
{
  const int lane = threadIdx.x & 63;
  const int wid = threadIdx.x >> 6;
  const int nBase = blockIdx.x * 256 + wid * 64;
  const int cc = lane & 15;
  const int kOff = (lane >> 4) * 8;

  bf16x8 b[4][4];
  #pragma unroll
  for (int n = 0; n < 4; ++n) {
    int c = nBase + n * 16 + cc;
    if (c > NA - 1) c = NA - 1;
    #pragma unroll
    for (int kk = 0; kk < 4; ++kk)
      b[n][kk] = *(const bf16x8*)(O + (size_t)c * FEAT + kk * 32 + kOff);
  }

  const int r0 = (lane >> 4) * 4;
  #pragma unroll
  for (int it = 0; it < 4; ++it) {
    const int iBase = blockIdx.y * 256 + it * 64;
    f32x4 acc[4][4];
    #pragma unroll
    for (int m = 0; m < 4; ++m)
      #pragma unroll
      for (int n = 0; n < 4; ++n)
        acc[m][n] = (f32x4){0.f, 0.f, 0.f, 0.f};

    #pragma unroll
    for (int kk = 0; kk < 4; ++kk) {
      bf16x8 a[4];
      #pragma unroll
      for (int m = 0; m < 4; ++m)
        a[m] = *(const bf16x8*)(Z + (size_t)(iBase + cc + m * 16) * FEAT + kk * 32 + kOff);
      #pragma unroll
      for (int m = 0; m < 4; ++m)
        #pragma unroll
        for (int n = 0; n < 4; ++n)
          acc[m][n] = __builtin_amdgcn_mfma_f32_16x16x32_bf16(a[m], b[n][kk], acc[m][n], 0, 0, 0);
    }

    #pragma unroll
    for (int n = 0; n < 4; ++n) {
      int col = nBase + n * 16 + cc;
      if (col < NA) {
        #pragma unroll
        for (int m = 0; m < 4; ++m) {
          #pragma unroll
          for (int r = 0; r < 4; ++r) {
            int row = iBase + m * 16 + r0 + r;
            __builtin_nontemporal_store(acc[m][n][r], &out[(size_t)row * NA + col]);
          }
        }
      }
    }
  }
}

static inline char* alignup(char* p, size_t a) {
  return (char*)(((uintptr_t)p + a - 1) & ~(uintptr_t)(a - 1));
}

extern "C" void kernel_launch(void* const* d_in, const int* in_sizes, int n_in,
                              void* d_out, int out_size, void* d_ws, size_t ws_size,
                              hipStream_t stream) {
  const float* x      = (const float*)d_in[0];
  const float* mashup = (const float*)d_in[1];
  const float* domain = (const float*)d_in[2];
  const float* api    = (const float*)d_in[3];
  const float* Wsde   = (const float*)d_in[4];
  const float* bsde   = (const float*)d_in[5];
  const float* Wval   = (const float*)d_in[6];
  const float* bval   = (const float*)d_in[7];
  const float* Wkey   = (const float*)d_in[8];
  const float* bkey   = (const float*)d_in[9];
  const float* Wsie   = (const float*)d_in[10];
  const float* bsie   = (const float*)d_in[11];
  const int* esrc     = (const int*)d_in[12];
  const int* edst     = (const int*)d_in[13];
  float* out = (float*)d_out;

  // workspace layout (~90 MB)
  char* p = (char*)d_ws;
  u8*     M0y8  = (u8*)p; p += (size_t)NM * FEAT;                 // 6.4MB
  u8*     y0a8  = (u8*)p; p += (size_t)NA * FEAT;                 // 6.4MB
  u8*     y01a8 = (u8*)p; p += (size_t)NA * FEAT;                 // 6.4MB
  u8*     Sy8   = (u8*)p; p += (size_t)NM * FEAT;                 // 6.4MB
  bf16_t* outA  = (bf16_t*)p; p += (size_t)NA * FEAT * 2;         // 12.8MB
  bf16_t* Obf   = (bf16_t*)p; p += (size_t)NA * FEAT * 2;         // 12.8MB
  u16*    adjm  = (u16*)p;    p += (size_t)NM * MD * 2;           // 12.8MB
  u16*    adja  = (u16*)p;    p += (size_t)NA * MD * 2;           // 12.8MB
  float*  vmi   = (float*)p;  p += (size_t)BATCH * FEAT * 4;
  float*  vkey  = (float*)p;  p += (size_t)ND * FEAT * 4;
  float*  vval  = (float*)p;  p += (size_t)ND * FEAT * 4;
  bf16_t* zm    = (bf16_t*)p; p += (size_t)BATCH * FEAT * 2;
  int* cnt_m = (int*)p; p += (size_t)NM * 4;
  int* cnt_a = (int*)p; p += (size_t)NA * 4;
  float* dm  = (float*)p; p += (size_t)NM * 4;
  float* da  = (float*)p; p += (size_t)NA * 4;
  int* bcur  = (int*)p; p += 512 * 4;
  p = alignup(p, 16);
  bf16_t* wt0 = (bf16_t*)p; p += (size_t)FEAT * KDIM * 2;
  bf16_t* wt1 = (bf16_t*)p; p += (size_t)FEAT * KDIM * 2;
  bf16_t* wt2 = (bf16_t*)p; p += (size_t)FEAT * KDIM * 2;
  bf16_t* wt3 = (bf16_t*)p; p += (size_t)FEAT * KDIM * 2;
  // rec (2*NBIN*CAP*4B = 16.1MB) overlays M0y8+y0a8+y01a8 (19.2MB): dead
  // before proj_all/prop write those (fill_ell2 completes first, same stream).
  uint32_t* rec = (uint32_t*)M0y8;

  hipMemsetAsync(bcur, 0, 512 * sizeof(int), stream);

  // ---- graph build (+ weight transpose fused into the same dispatch) ----
  fill_bin_wt<<<F1B + 512, 256, 0, stream>>>(esrc, edst, bcur, rec,
                                             Wsde, Wkey, Wval, Wsie,
                                             wt0, wt1, wt2, wt3);
  fill_ell2<<<2 * NBIN, 256, 0, stream>>>(rec, bcur, adjm, adja,
                                          cnt_m, cnt_a, dm, da);

  // ---- ALL projections (full-line A staging) ----
  proj_all<<<2 * PB128 + 16, 512, 0, stream>>>(
      mashup, api, x, domain, wt0, wt1, wt2, wt3,
      bsde, bkey, bval, bsie, M0y8, y0a8, vmi, vkey, vval, dm, da, outA);

  // ---- attention + LightGCN pass1, one dispatch ----
  attn_p1<<<BATCH + NA / 4, 256, 0, stream>>>(
      vmi, vkey, vval, zm,
      (const uint32_t*)M0y8, (const uint32_t*)y0a8, (uint32_t*)y01a8,
      adja, cnt_a, da);

  prop_p2<<<NM / 4, 256, 0, stream>>>((const uint32_t*)y01a8, (const uint32_t*)M0y8,
                                      (uint32_t*)Sy8, adjm, cnt_m, dm);
  prop_p3<<<NA / 4, 256, 0, stream>>>((const uint32_t*)Sy8, outA, Obf,
                                      adja, cnt_a, da);

  pred_mfma<<<dim3((NA + 255) / 256, BATCH / 256), 256, 0, stream>>>(zm, Obf, out);
}

// Round 20
// 377.864 us; speedup vs baseline: 1.0994x; 1.0033x over previous
//
#include <hip/hip_runtime.h>
#include <hip/hip_bf16.h>
#include <cstddef>
#include <cstdint>

#define NM 50000
#define NA 50000
#define ND 500
#define FEAT 128
#define KDIM 768
#define BATCH 1024
#define NEDGE 1600000
#define MD 128            // ELL row capacity (deg ~ Poisson(32); P(>128) ~ 1e-38)

#define NBIN 196          // ceil(50000/256) node bins of 256 nodes
#define CAP 10240         // records per bin (expected 8163, 23 sigma headroom)
#define F1B 400           // fill_bin blocks (edge part)
#define F1E (NEDGE / F1B) // 4000 edges per block (exact)

#define PB128 391         // ceil(50000/128) blocks per big projection (8 waves x 16 rows)
#define PKT   24          // K tiles (768/32)

typedef __bf16 bf16_t;
typedef bf16_t bf16x8 __attribute__((ext_vector_type(8)));
typedef bf16_t bf16x4 __attribute__((ext_vector_type(4)));
typedef float f32x4 __attribute__((ext_vector_type(4)));
typedef float f32x2 __attribute__((ext_vector_type(2)));
typedef unsigned short u16;
typedef unsigned char u8;

__device__ __forceinline__ float sigf(float x) { return 1.0f / (1.0f + __expf(-x)); }

// ---- fp8 e4m3 (OCP) helpers: HW v_cvt pack/unpack ----
__device__ __forceinline__ float4 dec4fp8(uint32_t w) {
  f32x2 lo = __builtin_amdgcn_cvt_pk_f32_fp8(w, false);
  f32x2 hi = __builtin_amdgcn_cvt_pk_f32_fp8(w, true);
  return make_float4(lo[0], lo[1], hi[0], hi[1]);
}
__device__ __forceinline__ u8 enc1fp8(float a) {
  return (u8)(__builtin_amdgcn_cvt_pk_fp8_f32(a, a, 0, false) & 0xff);
}

// ---- async global->LDS, 16B per lane (dest = wave-uniform base + lane*16) ----
__device__ __forceinline__ void gll16(const void* g, void* l) {
  __builtin_amdgcn_global_load_lds(
      (const __attribute__((address_space(1))) unsigned int*)g,
      (__attribute__((address_space(3))) unsigned int*)l, 16, 0, 0);
}

// ---------------- fill pass 1 + weight transpose, one dispatch ----------------
__global__ __launch_bounds__(256) void fill_bin_wt(
    const int* __restrict__ src, const int* __restrict__ dst,
    int* __restrict__ bcur, uint32_t* __restrict__ rec,
    const float* __restrict__ W0, const float* __restrict__ W1,
    const float* __restrict__ W2, const float* __restrict__ W3,
    bf16_t* __restrict__ T0, bf16_t* __restrict__ T1,
    bf16_t* __restrict__ T2, bf16_t* __restrict__ T3)
{
  __shared__ uint32_t edg[F1E];      // 16 KB
  __shared__ int hist[2 * NBIN];
  __shared__ int base[2 * NBIN];
  if (blockIdx.x >= F1B) {
    const int b = blockIdx.x - F1B;      // 0..511
    const float* W = (b < 128) ? W0 : (b < 256) ? W1 : (b < 384) ? W2 : W3;
    bf16_t* T      = (b < 128) ? T0 : (b < 256) ? T1 : (b < 384) ? T2 : T3;
    int c = b & 127;
    for (int k = threadIdx.x; k < KDIM; k += 256)
      T[(size_t)c * KDIM + k] = (bf16_t)W[(size_t)k * FEAT + c];
    return;
  }
  const int tid = threadIdx.x;
  for (int i = tid; i < 2 * NBIN; i += 256) hist[i] = 0;
  __syncthreads();
  const int e0 = blockIdx.x * F1E;
  for (int i = tid; i < F1E; i += 256) {
    int s = __builtin_nontemporal_load(&src[e0 + i]);
    int d = __builtin_nontemporal_load(&dst[e0 + i]);
    edg[i] = ((uint32_t)s << 16) | (uint32_t)d;
    atomicAdd(&hist[s >> 8], 1);
    atomicAdd(&hist[NBIN + (d >> 8)], 1);
  }
  __syncthreads();
  for (int i = tid; i < 2 * NBIN; i += 256) {
    int c = hist[i];
    base[i] = c ? atomicAdd(&bcur[i], c) : 0;
    hist[i] = 0;  // reuse as emit cursor
  }
  __syncthreads();
  for (int i = tid; i < F1E; i += 256) {
    uint32_t e = edg[i];
    int s = (int)(e >> 16), d = (int)(e & 0xffffu);
    int bm = s >> 8, ba = NBIN + (d >> 8);
    int rm = base[bm] + atomicAdd(&hist[bm], 1);
    int ra = base[ba] + atomicAdd(&hist[ba], 1);
    if (rm < CAP) rec[(size_t)bm * CAP + rm] = e;
    if (ra < CAP) rec[(size_t)ba * CAP + ra] = ((uint32_t)d << 16) | (uint32_t)s;
  }
}

// ---------------- fill pass 2: records -> ELL rows + degrees + dinv -----------
__global__ __launch_bounds__(256) void fill_ell2(
    const uint32_t* __restrict__ rec, const int* __restrict__ bcur,
    u16* __restrict__ adjm, u16* __restrict__ adja,
    int* __restrict__ cnt_m, int* __restrict__ cnt_a,
    float* __restrict__ dm, float* __restrict__ da)
{
  __shared__ int cnt256[256];
  const int g = blockIdx.x;                 // 0..2*NBIN-1
  const int side = g >= NBIN;
  const int bin = side ? g - NBIN : g;
  u16* adj = side ? adja : adjm;
  int* cnt = side ? cnt_a : cnt_m;
  float* dv = side ? da : dm;
  cnt256[threadIdx.x] = 0;
  __syncthreads();
  int n = bcur[g]; if (n > CAP) n = CAP;
  const uint32_t* rb = rec + (size_t)g * CAP;
  for (int i = threadIdx.x; i < n; i += 256) {
    uint32_t r = rb[i];
    int node = (int)(r >> 16);
    int rk = atomicAdd(&cnt256[node & 255], 1);
    if (rk < MD) adj[(size_t)node * MD + rk] = (u16)(r & 0xffffu);
  }
  __syncthreads();
  int node = bin * 256 + threadIdx.x;
  if (node < NM) {
    int c = cnt256[threadIdx.x];
    cnt[node] = c;
    dv[node] = c > 0 ? rsqrtf((float)c) : 0.f;
  }
}

// ---------------- projection, BM=128, 8 waves, 3-stage SINGLE-barrier ---------
// C = sigmoid(A[M,768] @ W + b). OM: 0 = fp32 out, 2 = fp8 out (row-scaled).
// Full-line A staging (r19). 3 buffers; loop = { vmcnt(own stage kt landed);
// s_barrier; issue stage kt+2 (overwrites (kt-1)%3 -- all waves past their
// compute(kt-1) per the barrier); compute kt }. ONE barrier per K-step:
// the end-of-compute barrier is redundant with 3 buffers.
template<int OM>
__device__ __forceinline__ void proj8(
    char* smraw,
    const float* __restrict__ A, const bf16_t* __restrict__ Wt,
    const float* __restrict__ bias, void* __restrict__ Cout, int M, int rowBase,
    const float* __restrict__ rowscale, bf16_t* __restrict__ C2)
{
  const int tid = threadIdx.x;
  const int lane = tid & 63;
  const int wid = tid >> 6;                 // 0..7

  // A staging: full 128B lines; lane l -> row l>>3, chunk (l&7) XOR (row&7)
  const int srow = lane >> 3;
  const int schunk = (lane & 7) ^ srow;
  int g0 = rowBase + wid * 16 + srow;     if (g0 > M - 1) g0 = M - 1;
  int g1 = rowBase + wid * 16 + 8 + srow; if (g1 > M - 1) g1 = M - 1;
  const float* asrc0 = A + (size_t)g0 * KDIM + schunk * 4;
  const float* asrc1 = A + (size_t)g1 * KDIM + schunk * 4;
  const bf16_t* bsrc = Wt + (size_t)(wid * 16 + (lane & 15)) * KDIM + ((lane >> 4) * 8);

  f32x4 acc[8];
  #pragma unroll
  for (int n = 0; n < 8; ++n) acc[n] = (f32x4){0.f, 0.f, 0.f, 0.f};

  // per-stage layout (24KB): [A: 8 waves x 2KB][B: 8 waves x 1KB]
  auto stage = [&](int kt, int s) {
    const int k0 = kt * 32;
    char* base = smraw + s * 24576;
    gll16(asrc0 + k0, base + wid * 2048);          // rows 0-7, full lines
    gll16(asrc1 + k0, base + wid * 2048 + 1024);   // rows 8-15, full lines
    gll16(bsrc + k0,  base + 16384 + wid * 1024);
  };

  stage(0, 0);
  stage(1, 1);

  // fragment read offsets (XOR-swizzled chunks)
  const int row16 = lane & 15, h = lane >> 4;
  const int rd1 = (row16 & 7) * 128 + ((row16 >> 3) ? 1024 : 0) +
                  ((2 * h) ^ (row16 & 7)) * 16;
  const int rd2 = (row16 & 7) * 128 + ((row16 >> 3) ? 1024 : 0) +
                  ((2 * h + 1) ^ (row16 & 7)) * 16;

  for (int kt = 0; kt < PKT; ++kt) {
    if (kt + 1 < PKT) {
      asm volatile("s_waitcnt vmcnt(3)" ::: "memory");   // own stage kt landed
    } else {
      asm volatile("s_waitcnt vmcnt(0)" ::: "memory");
    }
    __builtin_amdgcn_s_barrier();          // all waves: stage kt visible,
    asm volatile("" ::: "memory");         // compute kt-1 done everywhere
    if (kt + 2 < PKT) stage(kt + 2, (kt + 2) % 3);

    const char* bb = smraw + (kt % 3) * 24576;
    f32x4 lo = *(const f32x4*)(bb + wid * 2048 + rd1);
    f32x4 hi = *(const f32x4*)(bb + wid * 2048 + rd2);
    bf16x8 a;
    a[0] = (bf16_t)lo[0]; a[1] = (bf16_t)lo[1]; a[2] = (bf16_t)lo[2]; a[3] = (bf16_t)lo[3];
    a[4] = (bf16_t)hi[0]; a[5] = (bf16_t)hi[1]; a[6] = (bf16_t)hi[2]; a[7] = (bf16_t)hi[3];
    #pragma unroll
    for (int n = 0; n < 8; ++n) {
      bf16x8 bfr = *(const bf16x8*)(bb + 16384 + n * 1024 + lane * 16);
      acc[n] = __builtin_amdgcn_mfma_f32_16x16x32_bf16(a, bfr, acc[n], 0, 0, 0);
    }
    asm volatile("" ::: "memory");
  }

  // C frag layout: col=lane&15, row=(lane>>4)*4+reg
  const int r0 = (lane >> 4) * 4, cc = lane & 15;
  #pragma unroll
  for (int n = 0; n < 8; ++n) {
    int col = n * 16 + cc;
    float bb = bias[col];
    #pragma unroll
    for (int r = 0; r < 4; ++r) {
      int row = rowBase + wid * 16 + r0 + r;
      if (row < M) {
        float v = sigf(acc[n][r] + bb);
        float sc = rowscale ? rowscale[row] : 1.0f;
        if constexpr (OM == 2)
          ((u8*)Cout)[(size_t)row * FEAT + col] = enc1fp8(v * sc);
        else
          ((float*)Cout)[(size_t)row * FEAT + col] = v * sc;
        if (C2) C2[(size_t)row * FEAT + col] = (bf16_t)(0.25f * v);
      }
    }
  }
}

// ---------------- ALL projections, one dispatch (798 blocks x 512 thr) --------
__global__ __launch_bounds__(512, 2) void proj_all(
    const float* __restrict__ mashup, const float* __restrict__ api,
    const float* __restrict__ x, const float* __restrict__ domain,
    const bf16_t* __restrict__ wt0, const bf16_t* __restrict__ wt1,
    const bf16_t* __restrict__ wt2, const bf16_t* __restrict__ wt3,
    const float* __restrict__ bsde, const float* __restrict__ bkey,
    const float* __restrict__ bval, const float* __restrict__ bsie,
    u8* __restrict__ M0y8, u8* __restrict__ y0a8,
    float* __restrict__ vmi, float* __restrict__ vkey, float* __restrict__ vval,
    const float* __restrict__ dm, const float* __restrict__ da,
    bf16_t* __restrict__ outA)
{
  __shared__ alignas(16) char smem[3 * 24576];   // 72KB
  const int b = blockIdx.x;
  if (b < PB128)
    proj8<2>(smem, mashup, wt0, bsde, M0y8, NM, b * 128, dm, nullptr);
  else if (b < 2 * PB128)
    proj8<2>(smem, api, wt3, bsie, y0a8, NA, (b - PB128) * 128, da, outA);
  else if (b < 2 * PB128 + 8)
    proj8<0>(smem, x, wt0, bsde, vmi, BATCH, (b - 2 * PB128) * 128, nullptr, nullptr);
  else if (b < 2 * PB128 + 12)
    proj8<0>(smem, domain, wt1, bkey, vkey, ND, (b - 2 * PB128 - 8) * 128, nullptr, nullptr);
  else
    proj8<0>(smem, domain, wt2, bval, vval, ND, (b - 2 * PB128 - 12) * 128, nullptr, nullptr);
}

// ---------------- fp8 row-gather: half-wave per alternate neighbor ------------
__device__ __forceinline__ float4 gatherF8(const uint32_t* __restrict__ base32,
                                           const u16* __restrict__ row,
                                           int n, int half)
{
  float4 acc = make_float4(0.f, 0.f, 0.f, 0.f);
  int j = half;
  while (j + 14 < n) {
    int u[8];
    #pragma unroll
    for (int q = 0; q < 8; ++q) u[q] = row[j + 2 * q];
    uint32_t w[8];
    #pragma unroll
    for (int q = 0; q < 8; ++q) w[q] = base32[(size_t)u[q] * 32];
    #pragma unroll
    for (int q = 0; q < 8; ++q) {
      float4 v = dec4fp8(w[q]);
      acc.x += v.x; acc.y += v.y; acc.z += v.z; acc.w += v.w;
    }
    j += 16;
  }
  while (j < n) {
    float4 v = dec4fp8(base32[(size_t)row[j] * 32]);
    acc.x += v.x; acc.y += v.y; acc.z += v.z; acc.w += v.w;
    j += 2;
  }
  return acc;
}

#define REDUCE_HALVES(acc)                    \
  acc.x += __shfl_xor(acc.x, 32);             \
  acc.y += __shfl_xor(acc.y, 32);             \
  acc.z += __shfl_xor(acc.z, 32);             \
  acc.w += __shfl_xor(acc.w, 32);

// ---------------- fused: attention (blocks <1024) + prop pass1 (rest) ---------
__global__ __launch_bounds__(256) void attn_p1(
    const float* __restrict__ vmi, const float* __restrict__ vkey,
    const float* __restrict__ vval, bf16_t* __restrict__ zm,
    const uint32_t* __restrict__ M0y8, const uint32_t* __restrict__ y0a8,
    uint32_t* __restrict__ y01a8,
    const u16* __restrict__ adja, const int* __restrict__ cnt_a,
    const float* __restrict__ da)
{
  const int tid = threadIdx.x;
  if (blockIdx.x >= BATCH) {
    // ---- prop pass1 ----
    const int a = (blockIdx.x - BATCH) * 4 + (tid >> 6);
    const int lane = tid & 63;
    const int half = lane >> 5, sl = lane & 31;
    int n = cnt_a[a]; if (n > MD) n = MD;
    float4 acc = gatherF8(M0y8 + sl, adja + (size_t)a * MD, n, half);
    REDUCE_HALVES(acc)
    if (half == 0) {
      const float d = da[a];
      const float s2 = d * d;
      float4 b = dec4fp8(y0a8[(size_t)a * 32 + sl]);
      uint32_t o = __builtin_amdgcn_cvt_pk_fp8_f32(b.x + s2 * acc.x, b.y + s2 * acc.y, 0, false);
      o = __builtin_amdgcn_cvt_pk_fp8_f32(b.z + s2 * acc.z, b.w + s2 * acc.w, o, true);
      y01a8[(size_t)a * 32 + sl] = o;
    }
    return;
  }
  // ---- attention ----
  const int i = blockIdx.x;
  __shared__ float vs[FEAT];
  __shared__ float al[ND];
  __shared__ float red[4];
  __shared__ float ps[256];
  __shared__ float totS;
  if (tid < FEAT) vs[tid] = vmi[(size_t)i * FEAT + tid];
  __syncthreads();
  float part = 0.f;
  for (int j = tid; j < ND; j += 256) {
    const float* kr = vkey + (size_t)j * FEAT;
    float dot = 0.f;
    #pragma unroll 8
    for (int k = 0; k < FEAT; k += 4) {
      float4 kv = *(const float4*)(kr + k);
      dot += vs[k] * kv.x + vs[k + 1] * kv.y + vs[k + 2] * kv.z + vs[k + 3] * kv.w;
    }
    al[j] = dot;
    part += dot;
  }
  #pragma unroll
  for (int o = 32; o > 0; o >>= 1) part += __shfl_down(part, o, 64);
  if ((tid & 63) == 0) red[tid >> 6] = part;
  __syncthreads();
  if (tid == 0) totS = red[0] + red[1] + red[2] + red[3];
  const int f = tid & 127, h = tid >> 7;
  float s = 0.f;
  const float* vv = vval + (size_t)h * 250 * FEAT + f;
  #pragma unroll 5
  for (int j = 0; j < 250; ++j) s += al[h * 250 + j] * vv[(size_t)j * FEAT];
  ps[tid] = s;
  __syncthreads();
  if (tid < FEAT) {
    float z = 0.5f * ((ps[tid] + ps[128 + tid]) / totS + vs[tid]);
    zm[(size_t)i * FEAT + tid] = (bf16_t)z;
  }
}

// ---- pass2 (mashup side): Sy = M0y + dm^2 * sum_{a in N(m)} y01a[a] ----------
__global__ __launch_bounds__(256) void prop_p2(
    const uint32_t* __restrict__ y01a8, const uint32_t* __restrict__ M0y8,
    uint32_t* __restrict__ Sy8,
    const u16* __restrict__ adjm, const int* __restrict__ cnt_m,
    const float* __restrict__ dm)
{
  const int m = blockIdx.x * 4 + (threadIdx.x >> 6);
  const int lane = threadIdx.x & 63;
  const int half = lane >> 5, sl = lane & 31;
  int n = cnt_m[m]; if (n > MD) n = MD;
  float4 acc = gatherF8(y01a8 + sl, adjm + (size_t)m * MD, n, half);
  REDUCE_HALVES(acc)
  if (half == 0) {
    const float d = dm[m];
    const float s2 = d * d;
    float4 b = dec4fp8(M0y8[(size_t)m * 32 + sl]);
    uint32_t o = __builtin_amdgcn_cvt_pk_fp8_f32(b.x + s2 * acc.x, b.y + s2 * acc.y, 0, false);
    o = __builtin_amdgcn_cvt_pk_fp8_f32(b.z + s2 * acc.z, b.w + s2 * acc.w, o, true);
    Sy8[(size_t)m * 32 + sl] = o;
  }
}

// ---- pass3 (api side): O = 0.25*A0 + 0.25*da * sum_{m in N(a)} Sy[m] ---------
__global__ __launch_bounds__(256) void prop_p3(
    const uint32_t* __restrict__ Sy8, const bf16_t* __restrict__ outA,
    bf16_t* __restrict__ Obf,
    const u16* __restrict__ adja, const int* __restrict__ cnt_a,
    const float* __restrict__ da)
{
  const int a = blockIdx.x * 4 + (threadIdx.x >> 6);
  const int lane = threadIdx.x & 63;
  const int half = lane >> 5, sl = lane & 31;
  int n = cnt_a[a]; if (n > MD) n = MD;
  float4 acc = gatherF8(Sy8 + sl, adja + (size_t)a * MD, n, half);
  REDUCE_HALVES(acc)
  if (half == 0) {
    const float q = 0.25f * da[a];
    bf16x4 pv = *(const bf16x4*)(outA + (size_t)a * FEAT + 4 * sl);
    bf16x4 o;
    o[0] = (bf16_t)((float)pv[0] + q * acc.x);
    o[1] = (bf16_t)((float)pv[1] + q * acc.y);
    o[2] = (bf16_t)((float)pv[2] + q * acc.z);
    o[3] = (bf16_t)((float)pv[3] + q * acc.w);
    *(bf16x4*)(Obf + (size_t)a * FEAT + 4 * sl) = o;
  }
}

// ---------------- pred = Z[1024,128] @ O[50000,128]^T, bf16 MFMA --------------
__global__ __launch_bounds__(256) void pred_mfma(
    const bf16_t* __restrict__ Z, const bf16_t* __restrict__ O,
    float* __restrict__ out)
{
  const int lane = threadIdx.x & 63;
  const int wid = threadIdx.x >> 6;
  const int nBase = blockIdx.x * 256 + wid * 64;
  const int cc = lane & 15;
  const int kOff = (lane >> 4) * 8;

  bf16x8 b[4][4];
  #pragma unroll
  for (int n = 0; n < 4; ++n) {
    int c = nBase + n * 16 + cc;
    if (c > NA - 1) c = NA - 1;
    #pragma unroll
    for (int kk = 0; kk < 4; ++kk)
      b[n][kk] = *(const bf16x8*)(O + (size_t)c * FEAT + kk * 32 + kOff);
  }

  const int r0 = (lane >> 4) * 4;
  #pragma unroll
  for (int it = 0; it < 4; ++it) {
    const int iBase = blockIdx.y * 256 + it * 64;
    f32x4 acc[4][4];
    #pragma unroll
    for (int m = 0; m < 4; ++m)
      #pragma unroll
      for (int n = 0; n < 4; ++n)
        acc[m][n] = (f32x4){0.f, 0.f, 0.f, 0.f};

    #pragma unroll
    for (int kk = 0; kk < 4; ++kk) {
      bf16x8 a[4];
      #pragma unroll
      for (int m = 0; m < 4; ++m)
        a[m] = *(const bf16x8*)(Z + (size_t)(iBase + cc + m * 16) * FEAT + kk * 32 + kOff);
      #pragma unroll
      for (int m = 0; m < 4; ++m)
        #pragma unroll
        for (int n = 0; n < 4; ++n)
          acc[m][n] = __builtin_amdgcn_mfma_f32_16x16x32_bf16(a[m], b[n][kk], acc[m][n], 0, 0, 0);
    }

    #pragma unroll
    for (int n = 0; n < 4; ++n) {
      int col = nBase + n * 16 + cc;
      if (col < NA) {
        #pragma unroll
        for (int m = 0; m < 4; ++m) {
          #pragma unroll
          for (int r = 0; r < 4; ++r) {
            int row = iBase + m * 16 + r0 + r;
            __builtin_nontemporal_store(acc[m][n][r], &out[(size_t)row * NA + col]);
          }
        }
      }
    }
  }
}

static inline char* alignup(char* p, size_t a) {
  return (char*)(((uintptr_t)p + a - 1) & ~(uintptr_t)(a - 1));
}

extern "C" void kernel_launch(void* const* d_in, const int* in_sizes, int n_in,
                              void* d_out, int out_size, void* d_ws, size_t ws_size,
                              hipStream_t stream) {
  const float* x      = (const float*)d_in[0];
  const float* mashup = (const float*)d_in[1];
  const float* domain = (const float*)d_in[2];
  const float* api    = (const float*)d_in[3];
  const float* Wsde   = (const float*)d_in[4];
  const float* bsde   = (const float*)d_in[5];
  const float* Wval   = (const float*)d_in[6];
  const float* bval   = (const float*)d_in[7];
  const float* Wkey   = (const float*)d_in[8];
  const float* bkey   = (const float*)d_in[9];
  const float* Wsie   = (const float*)d_in[10];
  const float* bsie   = (const float*)d_in[11];
  const int* esrc     = (const int*)d_in[12];
  const int* edst     = (const int*)d_in[13];
  float* out = (float*)d_out;

  // workspace layout (~90 MB)
  char* p = (char*)d_ws;
  u8*     M0y8  = (u8*)p; p += (size_t)NM * FEAT;                 // 6.4MB
  u8*     y0a8  = (u8*)p; p += (size_t)NA * FEAT;                 // 6.4MB
  u8*     y01a8 = (u8*)p; p += (size_t)NA * FEAT;                 // 6.4MB
  u8*     Sy8   = (u8*)p; p += (size_t)NM * FEAT;                 // 6.4MB
  bf16_t* outA  = (bf16_t*)p; p += (size_t)NA * FEAT * 2;         // 12.8MB
  bf16_t* Obf   = (bf16_t*)p; p += (size_t)NA * FEAT * 2;         // 12.8MB
  u16*    adjm  = (u16*)p;    p += (size_t)NM * MD * 2;           // 12.8MB
  u16*    adja  = (u16*)p;    p += (size_t)NA * MD * 2;           // 12.8MB
  float*  vmi   = (float*)p;  p += (size_t)BATCH * FEAT * 4;
  float*  vkey  = (float*)p;  p += (size_t)ND * FEAT * 4;
  float*  vval  = (float*)p;  p += (size_t)ND * FEAT * 4;
  bf16_t* zm    = (bf16_t*)p; p += (size_t)BATCH * FEAT * 2;
  int* cnt_m = (int*)p; p += (size_t)NM * 4;
  int* cnt_a = (int*)p; p += (size_t)NA * 4;
  float* dm  = (float*)p; p += (size_t)NM * 4;
  float* da  = (float*)p; p += (size_t)NA * 4;
  int* bcur  = (int*)p; p += 512 * 4;
  p = alignup(p, 16);
  bf16_t* wt0 = (bf16_t*)p; p += (size_t)FEAT * KDIM * 2;
  bf16_t* wt1 = (bf16_t*)p; p += (size_t)FEAT * KDIM * 2;
  bf16_t* wt2 = (bf16_t*)p; p += (size_t)FEAT * KDIM * 2;
  bf16_t* wt3 = (bf16_t*)p; p += (size_t)FEAT * KDIM * 2;
  // rec (2*NBIN*CAP*4B = 16.1MB) overlays M0y8+y0a8+y01a8 (19.2MB): dead
  // before proj_all/prop write those (fill_ell2 completes first, same stream).
  uint32_t* rec = (uint32_t*)M0y8;

  hipMemsetAsync(bcur, 0, 512 * sizeof(int), stream);

  // ---- graph build (+ weight transpose fused into the same dispatch) ----
  fill_bin_wt<<<F1B + 512, 256, 0, stream>>>(esrc, edst, bcur, rec,
                                             Wsde, Wkey, Wval, Wsie,
                                             wt0, wt1, wt2, wt3);
  fill_ell2<<<2 * NBIN, 256, 0, stream>>>(rec, bcur, adjm, adja,
                                          cnt_m, cnt_a, dm, da);

  // ---- ALL projections (3-stage, single barrier per K-step) ----
  proj_all<<<2 * PB128 + 16, 512, 0, stream>>>(
      mashup, api, x, domain, wt0, wt1, wt2, wt3,
      bsde, bkey, bval, bsie, M0y8, y0a8, vmi, vkey, vval, dm, da, outA);

  // ---- attention + LightGCN pass1, one dispatch ----
  attn_p1<<<BATCH + NA / 4, 256, 0, stream>>>(
      vmi, vkey, vval, zm,
      (const uint32_t*)M0y8, (const uint32_t*)y0a8, (uint32_t*)y01a8,
      adja, cnt_a, da);

  prop_p2<<<NM / 4, 256, 0, stream>>>((const uint32_t*)y01a8, (const uint32_t*)M0y8,
                                      (uint32_t*)Sy8, adjm, cnt_m, dm);
  prop_p3<<<NA / 4, 256, 0, stream>>>((const uint32_t*)Sy8, outA, Obf,
                                      adja, cnt_a, da);

  pred_mfma<<<dim3((NA + 255) / 256, BATCH / 256), 256, 0, stream>>>(zm, Obf, out);
}

// Round 21
// 376.381 us; speedup vs baseline: 1.1037x; 1.0039x over previous
//
#include <hip/hip_runtime.h>
#include <hip/hip_bf16.h>
#include <cstddef>
#include <cstdint>

#define NM 50000
#define NA 50000
#define ND 500
#define FEAT 128
#define KDIM 768
#define BATCH 1024
#define NEDGE 1600000
#define MD 128            // ELL row capacity (deg ~ Poisson(32); P(>128) ~ 1e-38)

#define NBIN 196          // ceil(50000/256) node bins of 256 nodes
#define CAP 10240         // records per bin (expected 8163, 23 sigma headroom)
#define F1B 400           // fill_bin blocks (edge part)
#define F1E (NEDGE / F1B) // 4000 edges per block (exact)

#define PB128 391         // ceil(50000/128) blocks per big projection (8 waves x 16 rows)
#define PKT   24          // K tiles (768/32)

typedef __bf16 bf16_t;
typedef bf16_t bf16x8 __attribute__((ext_vector_type(8)));
typedef bf16_t bf16x4 __attribute__((ext_vector_type(4)));
typedef float f32x4 __attribute__((ext_vector_type(4)));
typedef float f32x2 __attribute__((ext_vector_type(2)));
typedef unsigned short u16;
typedef unsigned char u8;

__device__ __forceinline__ float sigf(float x) { return 1.0f / (1.0f + __expf(-x)); }

// ---- fp8 e4m3 (OCP) helpers: HW v_cvt pack/unpack ----
__device__ __forceinline__ float4 dec4fp8(uint32_t w) {
  f32x2 lo = __builtin_amdgcn_cvt_pk_f32_fp8(w, false);
  f32x2 hi = __builtin_amdgcn_cvt_pk_f32_fp8(w, true);
  return make_float4(lo[0], lo[1], hi[0], hi[1]);
}
__device__ __forceinline__ u8 enc1fp8(float a) {
  return (u8)(__builtin_amdgcn_cvt_pk_fp8_f32(a, a, 0, false) & 0xff);
}

// ---- async global->LDS, 16B per lane (dest = wave-uniform base + lane*16) ----
__device__ __forceinline__ void gll16(const void* g, void* l) {
  __builtin_amdgcn_global_load_lds(
      (const __attribute__((address_space(1))) unsigned int*)g,
      (__attribute__((address_space(3))) unsigned int*)l, 16, 0, 0);
}

// ---------------- fill pass 1 + weight transpose, one dispatch ----------------
__global__ __launch_bounds__(256) void fill_bin_wt(
    const int* __restrict__ src, const int* __restrict__ dst,
    int* __restrict__ bcur, uint32_t* __restrict__ rec,
    const float* __restrict__ W0, const float* __restrict__ W1,
    const float* __restrict__ W2, const float* __restrict__ W3,
    bf16_t* __restrict__ T0, bf16_t* __restrict__ T1,
    bf16_t* __restrict__ T2, bf16_t* __restrict__ T3)
{
  __shared__ uint32_t edg[F1E];      // 16 KB
  __shared__ int hist[2 * NBIN];
  __shared__ int base[2 * NBIN];
  if (blockIdx.x >= F1B) {
    const int b = blockIdx.x - F1B;      // 0..511
    const float* W = (b < 128) ? W0 : (b < 256) ? W1 : (b < 384) ? W2 : W3;
    bf16_t* T      = (b < 128) ? T0 : (b < 256) ? T1 : (b < 384) ? T2 : T3;
    int c = b & 127;
    for (int k = threadIdx.x; k < KDIM; k += 256)
      T[(size_t)c * KDIM + k] = (bf16_t)W[(size_t)k * FEAT + c];
    return;
  }
  const int tid = threadIdx.x;
  for (int i = tid; i < 2 * NBIN; i += 256) hist[i] = 0;
  __syncthreads();
  const int e0 = blockIdx.x * F1E;
  for (int i = tid; i < F1E; i += 256) {
    int s = __builtin_nontemporal_load(&src[e0 + i]);
    int d = __builtin_nontemporal_load(&dst[e0 + i]);
    edg[i] = ((uint32_t)s << 16) | (uint32_t)d;
    atomicAdd(&hist[s >> 8], 1);
    atomicAdd(&hist[NBIN + (d >> 8)], 1);
  }
  __syncthreads();
  for (int i = tid; i < 2 * NBIN; i += 256) {
    int c = hist[i];
    base[i] = c ? atomicAdd(&bcur[i], c) : 0;
    hist[i] = 0;  // reuse as emit cursor
  }
  __syncthreads();
  for (int i = tid; i < F1E; i += 256) {
    uint32_t e = edg[i];
    int s = (int)(e >> 16), d = (int)(e & 0xffffu);
    int bm = s >> 8, ba = NBIN + (d >> 8);
    int rm = base[bm] + atomicAdd(&hist[bm], 1);
    int ra = base[ba] + atomicAdd(&hist[ba], 1);
    if (rm < CAP) rec[(size_t)bm * CAP + rm] = e;
    if (ra < CAP) rec[(size_t)ba * CAP + ra] = ((uint32_t)d << 16) | (uint32_t)s;
  }
}

// ---------------- fill pass 2: records -> ELL rows + degrees + dinv -----------
__global__ __launch_bounds__(256) void fill_ell2(
    const uint32_t* __restrict__ rec, const int* __restrict__ bcur,
    u16* __restrict__ adjm, u16* __restrict__ adja,
    int* __restrict__ cnt_m, int* __restrict__ cnt_a,
    float* __restrict__ dm, float* __restrict__ da)
{
  __shared__ int cnt256[256];
  const int g = blockIdx.x;                 // 0..2*NBIN-1
  const int side = g >= NBIN;
  const int bin = side ? g - NBIN : g;
  u16* adj = side ? adja : adjm;
  int* cnt = side ? cnt_a : cnt_m;
  float* dv = side ? da : dm;
  cnt256[threadIdx.x] = 0;
  __syncthreads();
  int n = bcur[g]; if (n > CAP) n = CAP;
  const uint32_t* rb = rec + (size_t)g * CAP;
  for (int i = threadIdx.x; i < n; i += 256) {
    uint32_t r = rb[i];
    int node = (int)(r >> 16);
    int rk = atomicAdd(&cnt256[node & 255], 1);
    if (rk < MD) adj[(size_t)node * MD + rk] = (u16)(r & 0xffffu);
  }
  __syncthreads();
  int node = bin * 256 + threadIdx.x;
  if (node < NM) {
    int c = cnt256[threadIdx.x];
    cnt[node] = c;
    dv[node] = c > 0 ? rsqrtf((float)c) : 0.f;
  }
}

// ---------------- projection, BM=128, 8 waves, 3-stage single-barrier + setprio
// C = sigmoid(A[M,768] @ W + b). OM: 0 = fp32 out, 2 = fp8 out (row-scaled).
// Full-line A staging. 3 buffers; loop = { vmcnt(own stage kt); s_barrier;
// issue stage kt+2; setprio(1); compute kt; setprio(0) }. T5: waves in the
// MFMA cluster get scheduler priority over waves still issuing stages.
template<int OM>
__device__ __forceinline__ void proj8(
    char* smraw,
    const float* __restrict__ A, const bf16_t* __restrict__ Wt,
    const float* __restrict__ bias, void* __restrict__ Cout, int M, int rowBase,
    const float* __restrict__ rowscale, bf16_t* __restrict__ C2)
{
  const int tid = threadIdx.x;
  const int lane = tid & 63;
  const int wid = tid >> 6;                 // 0..7

  // A staging: full 128B lines; lane l -> row l>>3, chunk (l&7) XOR (row&7)
  const int srow = lane >> 3;
  const int schunk = (lane & 7) ^ srow;
  int g0 = rowBase + wid * 16 + srow;     if (g0 > M - 1) g0 = M - 1;
  int g1 = rowBase + wid * 16 + 8 + srow; if (g1 > M - 1) g1 = M - 1;
  const float* asrc0 = A + (size_t)g0 * KDIM + schunk * 4;
  const float* asrc1 = A + (size_t)g1 * KDIM + schunk * 4;
  const bf16_t* bsrc = Wt + (size_t)(wid * 16 + (lane & 15)) * KDIM + ((lane >> 4) * 8);

  f32x4 acc[8];
  #pragma unroll
  for (int n = 0; n < 8; ++n) acc[n] = (f32x4){0.f, 0.f, 0.f, 0.f};

  // per-stage layout (24KB): [A: 8 waves x 2KB][B: 8 waves x 1KB]
  auto stage = [&](int kt, int s) {
    const int k0 = kt * 32;
    char* base = smraw + s * 24576;
    gll16(asrc0 + k0, base + wid * 2048);          // rows 0-7, full lines
    gll16(asrc1 + k0, base + wid * 2048 + 1024);   // rows 8-15, full lines
    gll16(bsrc + k0,  base + 16384 + wid * 1024);
  };

  stage(0, 0);
  stage(1, 1);

  // fragment read offsets (XOR-swizzled chunks)
  const int row16 = lane & 15, h = lane >> 4;
  const int rd1 = (row16 & 7) * 128 + ((row16 >> 3) ? 1024 : 0) +
                  ((2 * h) ^ (row16 & 7)) * 16;
  const int rd2 = (row16 & 7) * 128 + ((row16 >> 3) ? 1024 : 0) +
                  ((2 * h + 1) ^ (row16 & 7)) * 16;

  for (int kt = 0; kt < PKT; ++kt) {
    if (kt + 1 < PKT) {
      asm volatile("s_waitcnt vmcnt(3)" ::: "memory");   // own stage kt landed
    } else {
      asm volatile("s_waitcnt vmcnt(0)" ::: "memory");
    }
    __builtin_amdgcn_s_barrier();          // stage kt visible everywhere;
    asm volatile("" ::: "memory");         // compute kt-1 done everywhere
    if (kt + 2 < PKT) stage(kt + 2, (kt + 2) % 3);

    const char* bb = smraw + (kt % 3) * 24576;
    f32x4 lo = *(const f32x4*)(bb + wid * 2048 + rd1);
    f32x4 hi = *(const f32x4*)(bb + wid * 2048 + rd2);
    bf16x8 a;
    a[0] = (bf16_t)lo[0]; a[1] = (bf16_t)lo[1]; a[2] = (bf16_t)lo[2]; a[3] = (bf16_t)lo[3];
    a[4] = (bf16_t)hi[0]; a[5] = (bf16_t)hi[1]; a[6] = (bf16_t)hi[2]; a[7] = (bf16_t)hi[3];
    __builtin_amdgcn_s_setprio(1);
    #pragma unroll
    for (int n = 0; n < 8; ++n) {
      bf16x8 bfr = *(const bf16x8*)(bb + 16384 + n * 1024 + lane * 16);
      acc[n] = __builtin_amdgcn_mfma_f32_16x16x32_bf16(a, bfr, acc[n], 0, 0, 0);
    }
    __builtin_amdgcn_s_setprio(0);
    asm volatile("" ::: "memory");
  }

  // C frag layout: col=lane&15, row=(lane>>4)*4+reg
  const int r0 = (lane >> 4) * 4, cc = lane & 15;
  #pragma unroll
  for (int n = 0; n < 8; ++n) {
    int col = n * 16 + cc;
    float bb = bias[col];
    #pragma unroll
    for (int r = 0; r < 4; ++r) {
      int row = rowBase + wid * 16 + r0 + r;
      if (row < M) {
        float v = sigf(acc[n][r] + bb);
        float sc = rowscale ? rowscale[row] : 1.0f;
        if constexpr (OM == 2)
          ((u8*)Cout)[(size_t)row * FEAT + col] = enc1fp8(v * sc);
        else
          ((float*)Cout)[(size_t)row * FEAT + col] = v * sc;
        if (C2) C2[(size_t)row * FEAT + col] = (bf16_t)(0.25f * v);
      }
    }
  }
}

// ---------------- ALL projections, one dispatch (798 blocks x 512 thr) --------
__global__ __launch_bounds__(512, 2) void proj_all(
    const float* __restrict__ mashup, const float* __restrict__ api,
    const float* __restrict__ x, const float* __restrict__ domain,
    const bf16_t* __restrict__ wt0, const bf16_t* __restrict__ wt1,
    const bf16_t* __restrict__ wt2, const bf16_t* __restrict__ wt3,
    const float* __restrict__ bsde, const float* __restrict__ bkey,
    const float* __restrict__ bval, const float* __restrict__ bsie,
    u8* __restrict__ M0y8, u8* __restrict__ y0a8,
    float* __restrict__ vmi, float* __restrict__ vkey, float* __restrict__ vval,
    const float* __restrict__ dm, const float* __restrict__ da,
    bf16_t* __restrict__ outA)
{
  __shared__ alignas(16) char smem[3 * 24576];   // 72KB
  const int b = blockIdx.x;
  if (b < PB128)
    proj8<2>(smem, mashup, wt0, bsde, M0y8, NM, b * 128, dm, nullptr);
  else if (b < 2 * PB128)
    proj8<2>(smem, api, wt3, bsie, y0a8, NA, (b - PB128) * 128, da, outA);
  else if (b < 2 * PB128 + 8)
    proj8<0>(smem, x, wt0, bsde, vmi, BATCH, (b - 2 * PB128) * 128, nullptr, nullptr);
  else if (b < 2 * PB128 + 12)
    proj8<0>(smem, domain, wt1, bkey, vkey, ND, (b - 2 * PB128 - 8) * 128, nullptr, nullptr);
  else
    proj8<0>(smem, domain, wt2, bval, vval, ND, (b - 2 * PB128 - 12) * 128, nullptr, nullptr);
}

// ---------------- fp8 row-gather: half-wave per alternate neighbor ------------
__device__ __forceinline__ float4 gatherF8(const uint32_t* __restrict__ base32,
                                           const u16* __restrict__ row,
                                           int n, int half)
{
  float4 acc = make_float4(0.f, 0.f, 0.f, 0.f);
  int j = half;
  while (j + 14 < n) {
    int u[8];
    #pragma unroll
    for (int q = 0; q < 8; ++q) u[q] = row[j + 2 * q];
    uint32_t w[8];
    #pragma unroll
    for (int q = 0; q < 8; ++q) w[q] = base32[(size_t)u[q] * 32];
    #pragma unroll
    for (int q = 0; q < 8; ++q) {
      float4 v = dec4fp8(w[q]);
      acc.x += v.x; acc.y += v.y; acc.z += v.z; acc.w += v.w;
    }
    j += 16;
  }
  while (j < n) {
    float4 v = dec4fp8(base32[(size_t)row[j] * 32]);
    acc.x += v.x; acc.y += v.y; acc.z += v.z; acc.w += v.w;
    j += 2;
  }
  return acc;
}

#define REDUCE_HALVES(acc)                    \
  acc.x += __shfl_xor(acc.x, 32);             \
  acc.y += __shfl_xor(acc.y, 32);             \
  acc.z += __shfl_xor(acc.z, 32);             \
  acc.w += __shfl_xor(acc.w, 32);

// ---------------- fused: attention (blocks <1024) + prop pass1 (rest) ---------
__global__ __launch_bounds__(256) void attn_p1(
    const float* __restrict__ vmi, const float* __restrict__ vkey,
    const float* __restrict__ vval, bf16_t* __restrict__ zm,
    const uint32_t* __restrict__ M0y8, const uint32_t* __restrict__ y0a8,
    uint32_t* __restrict__ y01a8,
    const u16* __restrict__ adja, const int* __restrict__ cnt_a,
    const float* __restrict__ da)
{
  const int tid = threadIdx.x;
  if (blockIdx.x >= BATCH) {
    // ---- prop pass1 ----
    const int a = (blockIdx.x - BATCH) * 4 + (tid >> 6);
    const int lane = tid & 63;
    const int half = lane >> 5, sl = lane & 31;
    int n = cnt_a[a]; if (n > MD) n = MD;
    float4 acc = gatherF8(M0y8 + sl, adja + (size_t)a * MD, n, half);
    REDUCE_HALVES(acc)
    if (half == 0) {
      const float d = da[a];
      const float s2 = d * d;
      float4 b = dec4fp8(y0a8[(size_t)a * 32 + sl]);
      uint32_t o = __builtin_amdgcn_cvt_pk_fp8_f32(b.x + s2 * acc.x, b.y + s2 * acc.y, 0, false);
      o = __builtin_amdgcn_cvt_pk_fp8_f32(b.z + s2 * acc.z, b.w + s2 * acc.w, o, true);
      y01a8[(size_t)a * 32 + sl] = o;
    }
    return;
  }
  // ---- attention ----
  const int i = blockIdx.x;
  __shared__ float vs[FEAT];
  __shared__ float al[ND];
  __shared__ float red[4];
  __shared__ float ps[256];
  __shared__ float totS;
  if (tid < FEAT) vs[tid] = vmi[(size_t)i * FEAT + tid];
  __syncthreads();
  float part = 0.f;
  for (int j = tid; j < ND; j += 256) {
    const float* kr = vkey + (size_t)j * FEAT;
    float dot = 0.f;
    #pragma unroll 8
    for (int k = 0; k < FEAT; k += 4) {
      float4 kv = *(const float4*)(kr + k);
      dot += vs[k] * kv.x + vs[k + 1] * kv.y + vs[k + 2] * kv.z + vs[k + 3] * kv.w;
    }
    al[j] = dot;
    part += dot;
  }
  #pragma unroll
  for (int o = 32; o > 0; o >>= 1) part += __shfl_down(part, o, 64);
  if ((tid & 63) == 0) red[tid >> 6] = part;
  __syncthreads();
  if (tid == 0) totS = red[0] + red[1] + red[2] + red[3];
  const int f = tid & 127, h = tid >> 7;
  float s = 0.f;
  const float* vv = vval + (size_t)h * 250 * FEAT + f;
  #pragma unroll 5
  for (int j = 0; j < 250; ++j) s += al[h * 250 + j] * vv[(size_t)j * FEAT];
  ps[tid] = s;
  __syncthreads();
  if (tid < FEAT) {
    float z = 0.5f * ((ps[tid] + ps[128 + tid]) / totS + vs[tid]);
    zm[(size_t)i * FEAT + tid] = (bf16_t)z;
  }
}

// ---- pass2 (mashup side): Sy = M0y + dm^2 * sum_{a in N(m)} y01a[a] ----------
__global__ __launch_bounds__(256) void prop_p2(
    const uint32_t* __restrict__ y01a8, const uint32_t* __restrict__ M0y8,
    uint32_t* __restrict__ Sy8,
    const u16* __restrict__ adjm, const int* __restrict__ cnt_m,
    const float* __restrict__ dm)
{
  const int m = blockIdx.x * 4 + (threadIdx.x >> 6);
  const int lane = threadIdx.x & 63;
  const int half = lane >> 5, sl = lane & 31;
  int n = cnt_m[m]; if (n > MD) n = MD;
  float4 acc = gatherF8(y01a8 + sl, adjm + (size_t)m * MD, n, half);
  REDUCE_HALVES(acc)
  if (half == 0) {
    const float d = dm[m];
    const float s2 = d * d;
    float4 b = dec4fp8(M0y8[(size_t)m * 32 + sl]);
    uint32_t o = __builtin_amdgcn_cvt_pk_fp8_f32(b.x + s2 * acc.x, b.y + s2 * acc.y, 0, false);
    o = __builtin_amdgcn_cvt_pk_fp8_f32(b.z + s2 * acc.z, b.w + s2 * acc.w, o, true);
    Sy8[(size_t)m * 32 + sl] = o;
  }
}

// ---- pass3 (api side): O = 0.25*A0 + 0.25*da * sum_{m in N(a)} Sy[m] ---------
__global__ __launch_bounds__(256) void prop_p3(
    const uint32_t* __restrict__ Sy8, const bf16_t* __restrict__ outA,
    bf16_t* __restrict__ Obf,
    const u16* __restrict__ adja, const int* __restrict__ cnt_a,
    const float* __restrict__ da)
{
  const int a = blockIdx.x * 4 + (threadIdx.x >> 6);
  const int lane = threadIdx.x & 63;
  const int half = lane >> 5, sl = lane & 31;
  int n = cnt_a[a]; if (n > MD) n = MD;
  float4 acc = gatherF8(Sy8 + sl, adja + (size_t)a * MD, n, half);
  REDUCE_HALVES(acc)
  if (half == 0) {
    const float q = 0.25f * da[a];
    bf16x4 pv = *(const bf16x4*)(outA + (size_t)a * FEAT + 4 * sl);
    bf16x4 o;
    o[0] = (bf16_t)((float)pv[0] + q * acc.x);
    o[1] = (bf16_t)((float)pv[1] + q * acc.y);
    o[2] = (bf16_t)((float)pv[2] + q * acc.z);
    o[3] = (bf16_t)((float)pv[3] + q * acc.w);
    *(bf16x4*)(Obf + (size_t)a * FEAT + 4 * sl) = o;
  }
}

// ---------------- pred = Z[1024,128] @ O[50000,128]^T, bf16 MFMA --------------
__global__ __launch_bounds__(256) void pred_mfma(
    const bf16_t* __restrict__ Z, const bf16_t* __restrict__ O,
    float* __restrict__ out)
{
  const int lane = threadIdx.x & 63;
  const int wid = threadIdx.x >> 6;
  const int nBase = blockIdx.x * 256 + wid * 64;
  const int cc = lane & 15;
  const int kOff = (lane >> 4) * 8;

  bf16x8 b[4][4];
  #pragma unroll
  for (int n = 0; n < 4; ++n) {
    int c = nBase + n * 16 + cc;
    if (c > NA - 1) c = NA - 1;
    #pragma unroll
    for (int kk = 0; kk < 4; ++kk)
      b[n][kk] = *(const bf16x8*)(O + (size_t)c * FEAT + kk * 32 + kOff);
  }

  const int r0 = (lane >> 4) * 4;
  #pragma unroll
  for (int it = 0; it < 4; ++it) {
    const int iBase = blockIdx.y * 256 + it * 64;
    f32x4 acc[4][4];
    #pragma unroll
    for (int m = 0; m < 4; ++m)
      #pragma unroll
      for (int n = 0; n < 4; ++n)
        acc[m][n] = (f32x4){0.f, 0.f, 0.f, 0.f};

    #pragma unroll
    for (int kk = 0; kk < 4; ++kk) {
      bf16x8 a[4];
      #pragma unroll
      for (int m = 0; m < 4; ++m)
        a[m] = *(const bf16x8*)(Z + (size_t)(iBase + cc + m * 16) * FEAT + kk * 32 + kOff);
      #pragma unroll
      for (int m = 0; m < 4; ++m)
        #pragma unroll
        for (int n = 0; n < 4; ++n)
          acc[m][n] = __builtin_amdgcn_mfma_f32_16x16x32_bf16(a[m], b[n][kk], acc[m][n], 0, 0, 0);
    }

    #pragma unroll
    for (int n = 0; n < 4; ++n) {
      int col = nBase + n * 16 + cc;
      if (col < NA) {
        #pragma unroll
        for (int m = 0; m < 4; ++m) {
          #pragma unroll
          for (int r = 0; r < 4; ++r) {
            int row = iBase + m * 16 + r0 + r;
            __builtin_nontemporal_store(acc[m][n][r], &out[(size_t)row * NA + col]);
          }
        }
      }
    }
  }
}

static inline char* alignup(char* p, size_t a) {
  return (char*)(((uintptr_t)p + a - 1) & ~(uintptr_t)(a - 1));
}

extern "C" void kernel_launch(void* const* d_in, const int* in_sizes, int n_in,
                              void* d_out, int out_size, void* d_ws, size_t ws_size,
                              hipStream_t stream) {
  const float* x      = (const float*)d_in[0];
  const float* mashup = (const float*)d_in[1];
  const float* domain = (const float*)d_in[2];
  const float* api    = (const float*)d_in[3];
  const float* Wsde   = (const float*)d_in[4];
  const float* bsde   = (const float*)d_in[5];
  const float* Wval   = (const float*)d_in[6];
  const float* bval   = (const float*)d_in[7];
  const float* Wkey   = (const float*)d_in[8];
  const float* bkey   = (const float*)d_in[9];
  const float* Wsie   = (const float*)d_in[10];
  const float* bsie   = (const float*)d_in[11];
  const int* esrc     = (const int*)d_in[12];
  const int* edst     = (const int*)d_in[13];
  float* out = (float*)d_out;

  // workspace layout (~90 MB)
  char* p = (char*)d_ws;
  u8*     M0y8  = (u8*)p; p += (size_t)NM * FEAT;                 // 6.4MB
  u8*     y0a8  = (u8*)p; p += (size_t)NA * FEAT;                 // 6.4MB
  u8*     y01a8 = (u8*)p; p += (size_t)NA * FEAT;                 // 6.4MB
  u8*     Sy8   = (u8*)p; p += (size_t)NM * FEAT;                 // 6.4MB
  bf16_t* outA  = (bf16_t*)p; p += (size_t)NA * FEAT * 2;         // 12.8MB
  bf16_t* Obf   = (bf16_t*)p; p += (size_t)NA * FEAT * 2;         // 12.8MB
  u16*    adjm  = (u16*)p;    p += (size_t)NM * MD * 2;           // 12.8MB
  u16*    adja  = (u16*)p;    p += (size_t)NA * MD * 2;           // 12.8MB
  float*  vmi   = (float*)p;  p += (size_t)BATCH * FEAT * 4;
  float*  vkey  = (float*)p;  p += (size_t)ND * FEAT * 4;
  float*  vval  = (float*)p;  p += (size_t)ND * FEAT * 4;
  bf16_t* zm    = (bf16_t*)p; p += (size_t)BATCH * FEAT * 2;
  int* cnt_m = (int*)p; p += (size_t)NM * 4;
  int* cnt_a = (int*)p; p += (size_t)NA * 4;
  float* dm  = (float*)p; p += (size_t)NM * 4;
  float* da  = (float*)p; p += (size_t)NA * 4;
  int* bcur  = (int*)p; p += 512 * 4;
  p = alignup(p, 16);
  bf16_t* wt0 = (bf16_t*)p; p += (size_t)FEAT * KDIM * 2;
  bf16_t* wt1 = (bf16_t*)p; p += (size_t)FEAT * KDIM * 2;
  bf16_t* wt2 = (bf16_t*)p; p += (size_t)FEAT * KDIM * 2;
  bf16_t* wt3 = (bf16_t*)p; p += (size_t)FEAT * KDIM * 2;
  // rec (2*NBIN*CAP*4B = 16.1MB) overlays M0y8+y0a8+y01a8 (19.2MB): dead
  // before proj_all/prop write those (fill_ell2 completes first, same stream).
  uint32_t* rec = (uint32_t*)M0y8;

  hipMemsetAsync(bcur, 0, 512 * sizeof(int), stream);

  // ---- graph build (+ weight transpose fused into the same dispatch) ----
  fill_bin_wt<<<F1B + 512, 256, 0, stream>>>(esrc, edst, bcur, rec,
                                             Wsde, Wkey, Wval, Wsie,
                                             wt0, wt1, wt2, wt3);
  fill_ell2<<<2 * NBIN, 256, 0, stream>>>(rec, bcur, adjm, adja,
                                          cnt_m, cnt_a, dm, da);

  // ---- ALL projections (3-stage, single barrier, setprio'd MFMA) ----
  proj_all<<<2 * PB128 + 16, 512, 0, stream>>>(
      mashup, api, x, domain, wt0, wt1, wt2, wt3,
      bsde, bkey, bval, bsie, M0y8, y0a8, vmi, vkey, vval, dm, da, outA);

  // ---- attention + LightGCN pass1, one dispatch ----
  attn_p1<<<BATCH + NA / 4, 256, 0, stream>>>(
      vmi, vkey, vval, zm,
      (const uint32_t*)M0y8, (const uint32_t*)y0a8, (uint32_t*)y01a8,
      adja, cnt_a, da);

  prop_p2<<<NM / 4, 256, 0, stream>>>((const uint32_t*)y01a8, (const uint32_t*)M0y8,
                                      (uint32_t*)Sy8, adjm, cnt_m, dm);
  prop_p3<<<NA / 4, 256, 0, stream>>>((const uint32_t*)Sy8, outA, Obf,
                                      adja, cnt_a, da);

  pred_mfma<<<dim3((NA + 255) / 256, BATCH / 256), 256, 0, stream>>>(zm, Obf, out);
}